// Round 9
// baseline (592.176 us; speedup 1.0000x reference)
//
#include <hip/hip_runtime.h>
#include <hip/hip_bf16.h>

typedef __hip_bfloat16 bf16;
typedef __attribute__((ext_vector_type(8))) short short8;   // 8 bf16 frag
typedef __attribute__((ext_vector_type(4))) float floatx4;  // MFMA C/D frag

#define HDIM 128
#define NCANON 27

__device__ __forceinline__ float b2f(bf16 v) { return __bfloat162float(v); }
__device__ __forceinline__ float s2f(short s) {
  return __uint_as_float(((unsigned int)(unsigned short)s) << 16);
}
__device__ __forceinline__ short f2s(float f) {
  return (short)__bfloat16_as_ushort(__float2bfloat16(f));
}

struct CanonDesc {
  const void* src[NCANON];
  int prefix[NCANON + 1];
};

// ---- canon with inlined dtype detect (block 0 publishes flag for the decoder)
__global__ void canon_kernel(CanonDesc d, const unsigned short* __restrict__ xraw,
                             int* __restrict__ flagOut, bf16* __restrict__ out, int total) {
  __shared__ int sflag;
  int tid = threadIdx.x;
  if (tid < 64) {
    unsigned short u = xraw[2 * tid];
    int e = (u >> 7) & 0xFF;
    int ok = (u == 0) || (e >= 100 && e <= 140);
    unsigned long long m = __ballot(ok);
    if (tid == 0) sflag = (__popcll(m) >= 48) ? 1 : 0;
  }
  __syncthreads();
  int isBf = sflag;
  if (blockIdx.x == 0 && tid == 0) flagOut[0] = isBf;
  int t = blockIdx.x * 256 + tid;
  if (t >= total) return;
  int lo = 0, hi = NCANON;
  while (lo + 1 < hi) { int mid = (lo + hi) >> 1; if (d.prefix[mid] <= t) lo = mid; else hi = mid; }
  int off = t - d.prefix[lo];
  out[t] = isBf ? ((const bf16*)d.src[lo])[off]
                : __float2bfloat16(((const float*)d.src[lo])[off]);
}

// ---------------------------------------------------------------- CSR build
__global__ void hist_kernel(const int* __restrict__ dst, int* __restrict__ cnt, int E) {
  int e = blockIdx.x * 256 + threadIdx.x;
  if (e < E) atomicAdd(&cnt[dst[e]], 1);
}

__global__ void scan1_kernel(const int* __restrict__ cnt, int* __restrict__ bsum, int n) {
  int tid = threadIdx.x, lane = tid & 63, wave = tid >> 6;
  int i = blockIdx.x * 256 + tid;
  int v = (i < n) ? cnt[i] : 0;
  #pragma unroll
  for (int d = 32; d; d >>= 1) v += __shfl_down(v, d);
  __shared__ int ws[4];
  if (lane == 0) ws[wave] = v;
  __syncthreads();
  if (tid == 0) bsum[blockIdx.x] = ws[0] + ws[1] + ws[2] + ws[3];
}

__global__ void scan2_kernel(int* __restrict__ bsum, int nb) {   // nb <= 128; 64 threads
  int lane = threadIdx.x;
  int a0 = (lane < nb) ? bsum[lane] : 0;
  int b0 = (64 + lane < nb) ? bsum[64 + lane] : 0;
  int a = a0, b = b0;
  #pragma unroll
  for (int d = 1; d < 64; d <<= 1) { int t = __shfl_up(a, d); if (lane >= d) a += t; }
  int totA = __shfl(a, 63);
  #pragma unroll
  for (int d = 1; d < 64; d <<= 1) { int t = __shfl_up(b, d); if (lane >= d) b += t; }
  int totB = __shfl(b, 63);
  if (lane < nb) bsum[lane] = a - a0;
  if (64 + lane < nb) bsum[64 + lane] = b - b0 + totA;
  if (lane == 0) bsum[nb] = totA + totB;
}

__global__ void scan3_kernel(const int* __restrict__ cnt, const int* __restrict__ bsum,
                             int* __restrict__ row_start, int n, int nb) {
  __shared__ int sh[256];
  int tid = threadIdx.x;
  int i = blockIdx.x * 256 + tid;
  int v = (i < n) ? cnt[i] : 0;
  sh[tid] = v;
  __syncthreads();
  #pragma unroll
  for (int off = 1; off < 256; off <<= 1) {
    int t = (tid >= off) ? sh[tid - off] : 0;
    __syncthreads();
    sh[tid] += t;
    __syncthreads();
  }
  if (i < n) row_start[i] = bsum[blockIdx.x] + sh[tid] - v;
  if (blockIdx.x == 0 && tid == 0) row_start[n] = bsum[nb];
}

__global__ void scatter_kernel(const int* __restrict__ src, const int* __restrict__ dst,
                               const int* __restrict__ row_start, int* __restrict__ cursor,
                               int* __restrict__ sortedE, int* __restrict__ srcS,
                               int* __restrict__ dstS, int E) {
  int e = blockIdx.x * 256 + threadIdx.x;
  if (e < E) {
    int d = dst[e];
    int pos = row_start[d] + atomicAdd(&cursor[d], 1);
    sortedE[pos] = e;
    srcS[pos] = src[e];
    dstS[pos] = d;
  }
}

// --------- type permutation: single-block atomic-free stable counting sort
__global__ void __launch_bounds__(1024) tsort_kernel(const int* __restrict__ types,
                                                     int* __restrict__ ts,
                                                     int* __restrict__ perm, int n) {
  __shared__ int wc[16][3];
  __shared__ int base[3];
  int tid = threadIdx.x, lane = tid & 63, wave = tid >> 6;
  int c0 = 0, c1 = 0, c2 = 0;
  for (int i = tid; i < n; i += 1024) {
    int t = types[i];
    c0 += (t == 0); c1 += (t == 1); c2 += (t == 2);
  }
  #pragma unroll
  for (int d = 32; d; d >>= 1) {
    c0 += __shfl_down(c0, d); c1 += __shfl_down(c1, d); c2 += __shfl_down(c2, d);
  }
  if (lane == 0) { wc[wave][0] = c0; wc[wave][1] = c1; wc[wave][2] = c2; }
  __syncthreads();
  if (tid == 0) {
    int t0 = 0, t1 = 0;
    for (int w = 0; w < 16; w++) { t0 += wc[w][0]; t1 += wc[w][1]; }
    ts[0] = 0; ts[1] = t0; ts[2] = t0 + t1; ts[3] = n;
    base[0] = 0; base[1] = t0; base[2] = t0 + t1;
  }
  __syncthreads();
  for (int i0 = 0; i0 < n; i0 += 1024) {
    int i = i0 + tid;
    int t = (i < n) ? types[i] : -1;
    unsigned long long m0 = __ballot(t == 0);
    unsigned long long m1 = __ballot(t == 1);
    unsigned long long m2 = __ballot(t == 2);
    if (lane == 0) { wc[wave][0] = __popcll(m0); wc[wave][1] = __popcll(m1); wc[wave][2] = __popcll(m2); }
    __syncthreads();
    if (i < n) {
      unsigned long long mt = (t == 0) ? m0 : ((t == 1) ? m1 : m2);
      unsigned long long below = (lane == 0) ? 0ull : ((1ull << lane) - 1ull);
      int r = __popcll(mt & below);
      int woff = 0;
      for (int w = 0; w < wave; w++) woff += wc[w][t];
      perm[base[t] + woff + r] = i;
    }
    __syncthreads();
    if (tid == 0) {
      int a0 = 0, a1 = 0, a2 = 0;
      for (int w = 0; w < 16; w++) { a0 += wc[w][0]; a1 += wc[w][1]; a2 += wc[w][2]; }
      base[0] += a0; base[1] += a1; base[2] += a2;
    }
    __syncthreads();
  }
}

// -------------------------------------------------- fused weight pre-pack (B-frag order)
struct PackJob { const bf16* src; bf16* dst; int Ksrc; int KS; int srcCols; };
struct PackJobs { PackJob j[40]; };

__global__ void pack_all_kernel(PackJobs J) {
  PackJob job = J.j[blockIdx.y];
  int idx = blockIdx.x * 256 + threadIdx.x;
  int total = 8 * job.KS * 64;
  if (idx >= total) return;
  int lane = idx & 63;
  int ks = (idx >> 6) % job.KS;
  int ct = idx / (64 * job.KS);
  bf16* o = job.dst + (size_t)idx * 8;
  int ncol = ct * 16 + (lane & 15);
  int kb = ks * 32 + ((lane >> 4) & 3) * 8;
  #pragma unroll
  for (int jj = 0; jj < 8; jj++) {
    int k = kb + jj;
    o[jj] = (k < job.Ksrc && ncol < job.srcCols)
              ? job.src[(size_t)k * job.srcCols + ncol] : __float2bfloat16(0.f);
  }
}

// ------------- per-node Y = h @ W1a / W1b (bf16 out) + zero m_node (y==0 blocks)
__global__ void __launch_bounds__(256) ygemm_kernel(
    const bf16* __restrict__ X,
    const bf16* __restrict__ WpA, const bf16* __restrict__ WpB,
    bf16* __restrict__ outA, bf16* __restrict__ outB,
    float* __restrict__ mnode, int M) {
  const bf16* Wp = blockIdx.y ? WpB : WpA;
  bf16* outp = blockIdx.y ? outB : outA;
  constexpr int BM = 64, RT = 4, SK = 136;
  __shared__ bf16 Zt[BM * SK];
  const int tid = threadIdx.x;
  const int lane = tid & 63, wave = tid >> 6, colq = lane & 15, quad = lane >> 4;
  const int row0 = blockIdx.x * BM;
  if (blockIdx.y == 0) {                    // zero this tile's m_node rows
    float4 z = {0.f, 0.f, 0.f, 0.f};
    for (int i = tid; i < BM * 32; i += 256) {
      int row = i >> 5, q = i & 31;
      int gr = row0 + row;
      if (gr < M) *(float4*)(mnode + (size_t)gr * HDIM + q * 4) = z;
    }
  }
  {
    int row = tid >> 2, sub = tid & 3;
    int gr = row0 + row;
    bool ok = gr < M;
    #pragma unroll
    for (int j = 0; j < 4; j++) {
      int seg = j * 4 + sub;
      uint4 v = {0u, 0u, 0u, 0u};
      if (ok) v = *(const uint4*)(X + (size_t)gr * HDIM + seg * 8);
      *(uint4*)(&Zt[row * SK + seg * 8]) = v;
    }
  }
  __syncthreads();
  floatx4 acc[RT][2];
  #pragma unroll
  for (int rt = 0; rt < RT; rt++)
    #pragma unroll
    for (int c = 0; c < 2; c++) acc[rt][c] = (floatx4){0.f, 0.f, 0.f, 0.f};
  #pragma unroll
  for (int ks = 0; ks < 4; ks++) {
    short8 bfr0 = *(const short8*)(Wp + (((size_t)(wave * 2 + 0) * 4 + ks) * 64 + lane) * 8);
    short8 bfr1 = *(const short8*)(Wp + (((size_t)(wave * 2 + 1) * 4 + ks) * 64 + lane) * 8);
    #pragma unroll
    for (int rt = 0; rt < RT; rt++) {
      short8 a = *(const short8*)(&Zt[(rt * 16 + colq) * SK + ks * 32 + quad * 8]);
      acc[rt][0] = __builtin_amdgcn_mfma_f32_16x16x32_bf16(a, bfr0, acc[rt][0], 0, 0, 0);
      acc[rt][1] = __builtin_amdgcn_mfma_f32_16x16x32_bf16(a, bfr1, acc[rt][1], 0, 0, 0);
    }
  }
  #pragma unroll
  for (int c = 0; c < 2; c++) {
    int col = wave * 32 + c * 16 + colq;
    #pragma unroll
    for (int rt = 0; rt < RT; rt++)
      #pragma unroll
      for (int r = 0; r < 4; r++) {
        int grow = row0 + rt * 16 + quad * 4 + r;
        if (grow < M) outp[(size_t)grow * HDIM + col] = __float2bfloat16(acc[rt][c][r]);
      }
  }
}

// ----------------------- edge-update + fused dst-segment aggregation
// out = h_e_old + (ReLU(h_e @ W1c + ysum + b1) @ W2 + b2); m_node[dst] += out (f32)
// ysum enters as the MFMA C-operand (per-lane gathered bf16 loads; no LDS round-trip).
// Zt part1 @128 = h_e (becomes out in-place); Hid uses part0 after GEMM1.
template<int BM, bool WRITE_HE>
__global__ void __launch_bounds__(256) eu_kernel(
    const bf16* __restrict__ he, const bf16* __restrict__ ysrc, const bf16* __restrict__ ydst,
    const int* __restrict__ srcS, const int* __restrict__ dstS,
    const bf16* __restrict__ W1p, const bf16* __restrict__ b1v,
    const bf16* __restrict__ W2p, const bf16* __restrict__ b2v,
    bf16* __restrict__ outp, float* __restrict__ mnode, int M) {
  constexpr int RT = BM / 16;
  constexpr int SK = 264;
  __shared__ bf16 Zt[BM * SK];
  __shared__ int dstLds[BM];
  const int tid = threadIdx.x;
  const int lane = tid & 63, wave = tid >> 6, colq = lane & 15, quad = lane >> 4;
  const int row0 = blockIdx.x * BM;

  // ---- acc init = ysum (C-layout gathered loads; issues early, overlaps staging)
  floatx4 acc[RT][2];
  #pragma unroll
  for (int rt = 0; rt < RT; rt++)
    #pragma unroll
    for (int r = 0; r < 4; r++) {
      int grow = row0 + rt * 16 + quad * 4 + r;
      float v0 = 0.f, v1 = 0.f;
      if (grow < M) {
        int g0 = srcS[grow], g1 = dstS[grow];
        int col0 = wave * 32 + colq;
        const bf16* ys = ysrc + (size_t)g0 * HDIM + col0;
        const bf16* yd = ydst + (size_t)g1 * HDIM + col0;
        v0 = b2f(ys[0]) + b2f(yd[0]);
        v1 = b2f(ys[16]) + b2f(yd[16]);
      }
      acc[rt][0][r] = v0;
      acc[rt][1][r] = v1;
    }

  // ---- stage h_e (contiguous, dst-sorted) into part1
  {
    constexpr int TPR = 256 / BM;            // threads per row (8 for BM=32)
    int row = tid / TPR, sub = tid % TPR;
    int gr = row0 + row;
    bool ok = gr < M;
    if (sub == 0) dstLds[row] = ok ? dstS[gr] : -1;
    #pragma unroll
    for (int j = 0; j < 16 / TPR; j++) {
      int seg = j * TPR + sub;
      uint4 v = {0u, 0u, 0u, 0u};
      if (ok) v = *(const uint4*)(he + (size_t)gr * HDIM + seg * 8);
      *(uint4*)(&Zt[row * SK + 128 + seg * 8]) = v;
    }
  }
  __syncthreads();

  // ---- GEMM1: acc += h_e @ W1c
  #pragma unroll
  for (int ks = 0; ks < 4; ks++) {
    short8 bfr0 = *(const short8*)(W1p + (((size_t)(wave * 2 + 0) * 4 + ks) * 64 + lane) * 8);
    short8 bfr1 = *(const short8*)(W1p + (((size_t)(wave * 2 + 1) * 4 + ks) * 64 + lane) * 8);
    #pragma unroll
    for (int rt = 0; rt < RT; rt++) {
      short8 a = *(const short8*)(&Zt[(rt * 16 + colq) * SK + 128 + ks * 32 + quad * 8]);
      acc[rt][0] = __builtin_amdgcn_mfma_f32_16x16x32_bf16(a, bfr0, acc[rt][0], 0, 0, 0);
      acc[rt][1] = __builtin_amdgcn_mfma_f32_16x16x32_bf16(a, bfr1, acc[rt][1], 0, 0, 0);
    }
  }
  // GEMM1 epilogue: Hid = ReLU(acc + b1) -> part0 (previously unused)
  #pragma unroll
  for (int c = 0; c < 2; c++) {
    int col = wave * 32 + c * 16 + colq;
    float bv = b2f(b1v[col]);
    #pragma unroll
    for (int rt = 0; rt < RT; rt++)
      #pragma unroll
      for (int r = 0; r < 4; r++) {
        int lrow = rt * 16 + quad * 4 + r;
        Zt[lrow * SK + col] = __float2bfloat16(fmaxf(acc[rt][c][r] + bv, 0.f));
      }
  }
  __syncthreads();

  // ---- GEMM2: out = Hid @ W2 + b2 + h_e
  floatx4 acc2[RT][2];
  #pragma unroll
  for (int rt = 0; rt < RT; rt++)
    #pragma unroll
    for (int c = 0; c < 2; c++) acc2[rt][c] = (floatx4){0.f, 0.f, 0.f, 0.f};
  #pragma unroll
  for (int ks = 0; ks < 4; ks++) {
    short8 bfr0 = *(const short8*)(W2p + (((size_t)(wave * 2 + 0) * 4 + ks) * 64 + lane) * 8);
    short8 bfr1 = *(const short8*)(W2p + (((size_t)(wave * 2 + 1) * 4 + ks) * 64 + lane) * 8);
    #pragma unroll
    for (int rt = 0; rt < RT; rt++) {
      short8 a = *(const short8*)(&Zt[(rt * 16 + colq) * SK + ks * 32 + quad * 8]);
      acc2[rt][0] = __builtin_amdgcn_mfma_f32_16x16x32_bf16(a, bfr0, acc2[rt][0], 0, 0, 0);
      acc2[rt][1] = __builtin_amdgcn_mfma_f32_16x16x32_bf16(a, bfr1, acc2[rt][1], 0, 0, 0);
    }
  }
  // epilogue: write out into part1 (for segsum) and optionally to global
  #pragma unroll
  for (int c = 0; c < 2; c++) {
    int col = wave * 32 + c * 16 + colq;
    float bv = b2f(b2v[col]);
    #pragma unroll
    for (int rt = 0; rt < RT; rt++)
      #pragma unroll
      for (int r = 0; r < 4; r++) {
        int lrow = rt * 16 + quad * 4 + r;
        int grow = row0 + lrow;
        float v = acc2[rt][c][r] + bv + b2f(Zt[lrow * SK + 128 + col]);
        bf16 vb = __float2bfloat16(v);
        Zt[lrow * SK + 128 + col] = vb;
        if (WRITE_HE && grow < M) outp[(size_t)grow * HDIM + col] = vb;
      }
  }
  __syncthreads();

  // fused aggregation: two halves, 256 threads; boundary runs atomicAdd
  {
    int col = tid & 127;
    int half = tid >> 7;
    int rbeg = half * (BM / 2), rend = rbeg + (BM / 2);
    float s = 0.f;
    int runDst = dstLds[rbeg];
    bool touchStart = true;
    for (int r = rbeg; r < rend; r++) {
      int d = dstLds[r];
      if (d != runDst) {
        if (runDst >= 0) {
          float* mp = &mnode[(size_t)runDst * HDIM + col];
          if (touchStart) atomicAdd(mp, s); else *mp = s;
        }
        runDst = d; s = 0.f; touchStart = false;
      }
      s += b2f(Zt[r * SK + 128 + col]);
    }
    if (runDst >= 0) atomicAdd(&mnode[(size_t)runDst * HDIM + col], s);
  }
}

// ----------------------- fused node update + fusion MLP (nu + fu)
__global__ void __launch_bounds__(256) node_kernel(
    const bf16* __restrict__ h_nodes, const float* __restrict__ mnode,
    const bf16* __restrict__ nuW1, const bf16* __restrict__ nuB1,
    const bf16* __restrict__ nuW2, const bf16* __restrict__ nuB2,
    const bf16* __restrict__ fuW1, const bf16* __restrict__ fuB1,
    const bf16* __restrict__ fuW2, const bf16* __restrict__ fuB2,
    bf16* __restrict__ outp, int M) {
  constexpr int BM = 64, RT = 4, SK = 264;
  __shared__ bf16 Zt[BM * SK];
  const int tid = threadIdx.x;
  const int lane = tid & 63, wave = tid >> 6, colq = lane & 15, quad = lane >> 4;
  const int row0 = blockIdx.x * BM;
  {
    int row = tid >> 2, sub = tid & 3;
    int gr = row0 + row;
    bool ok = gr < M;
    #pragma unroll
    for (int j = 0; j < 8; j++) {
      int c = j * 4 + sub;
      int part = c >> 4, seg = c & 15;
      if (part == 0) {
        uint4 v = {0u, 0u, 0u, 0u};
        if (ok) v = *(const uint4*)(h_nodes + (size_t)gr * HDIM + seg * 8);
        *(uint4*)(&Zt[row * SK + seg * 8]) = v;
      } else {
        short8 o = {0, 0, 0, 0, 0, 0, 0, 0};
        if (ok) {
          const float* mp = mnode + (size_t)gr * HDIM + seg * 8;
          #pragma unroll
          for (int k = 0; k < 8; k++) o[k] = f2s(mp[k]);
        }
        *(short8*)(&Zt[row * SK + 128 + seg * 8]) = o;
      }
    }
  }
  __syncthreads();

  floatx4 acc[RT][2];
  #pragma unroll
  for (int rt = 0; rt < RT; rt++)
    #pragma unroll
    for (int c = 0; c < 2; c++) acc[rt][c] = (floatx4){0.f, 0.f, 0.f, 0.f};
  #pragma unroll
  for (int ks = 0; ks < 8; ks++) {
    short8 bfr0 = *(const short8*)(nuW1 + (((size_t)(wave * 2 + 0) * 8 + ks) * 64 + lane) * 8);
    short8 bfr1 = *(const short8*)(nuW1 + (((size_t)(wave * 2 + 1) * 8 + ks) * 64 + lane) * 8);
    #pragma unroll
    for (int rt = 0; rt < RT; rt++) {
      short8 a = *(const short8*)(&Zt[(rt * 16 + colq) * SK + ks * 32 + quad * 8]);
      acc[rt][0] = __builtin_amdgcn_mfma_f32_16x16x32_bf16(a, bfr0, acc[rt][0], 0, 0, 0);
      acc[rt][1] = __builtin_amdgcn_mfma_f32_16x16x32_bf16(a, bfr1, acc[rt][1], 0, 0, 0);
    }
  }
  __syncthreads();
  #pragma unroll
  for (int c = 0; c < 2; c++) {
    int col = wave * 32 + c * 16 + colq;
    float bv = b2f(nuB1[col]);
    #pragma unroll
    for (int rt = 0; rt < RT; rt++)
      #pragma unroll
      for (int r = 0; r < 4; r++)
        Zt[(rt * 16 + quad * 4 + r) * SK + 128 + col] =
            __float2bfloat16(fmaxf(acc[rt][c][r] + bv, 0.f));
  }
  __syncthreads();

  #pragma unroll
  for (int rt = 0; rt < RT; rt++)
    #pragma unroll
    for (int c = 0; c < 2; c++) acc[rt][c] = (floatx4){0.f, 0.f, 0.f, 0.f};
  #pragma unroll
  for (int ks = 0; ks < 4; ks++) {
    short8 bfr0 = *(const short8*)(nuW2 + (((size_t)(wave * 2 + 0) * 4 + ks) * 64 + lane) * 8);
    short8 bfr1 = *(const short8*)(nuW2 + (((size_t)(wave * 2 + 1) * 4 + ks) * 64 + lane) * 8);
    #pragma unroll
    for (int rt = 0; rt < RT; rt++) {
      short8 a = *(const short8*)(&Zt[(rt * 16 + colq) * SK + 128 + ks * 32 + quad * 8]);
      acc[rt][0] = __builtin_amdgcn_mfma_f32_16x16x32_bf16(a, bfr0, acc[rt][0], 0, 0, 0);
      acc[rt][1] = __builtin_amdgcn_mfma_f32_16x16x32_bf16(a, bfr1, acc[rt][1], 0, 0, 0);
    }
  }
  #pragma unroll
  for (int c = 0; c < 2; c++) {
    int col = wave * 32 + c * 16 + colq;
    float bv = b2f(nuB2[col]);
    #pragma unroll
    for (int rt = 0; rt < RT; rt++)
      #pragma unroll
      for (int r = 0; r < 4; r++) {
        int lrow = rt * 16 + quad * 4 + r;
        float v = acc[rt][c][r] + bv + b2f(Zt[lrow * SK + col]);
        Zt[lrow * SK + col] = __float2bfloat16(v);
      }
  }
  __syncthreads();

  #pragma unroll
  for (int rt = 0; rt < RT; rt++)
    #pragma unroll
    for (int c = 0; c < 2; c++) acc[rt][c] = (floatx4){0.f, 0.f, 0.f, 0.f};
  #pragma unroll
  for (int ks = 0; ks < 4; ks++) {
    short8 bfr0 = *(const short8*)(fuW1 + (((size_t)(wave * 2 + 0) * 4 + ks) * 64 + lane) * 8);
    short8 bfr1 = *(const short8*)(fuW1 + (((size_t)(wave * 2 + 1) * 4 + ks) * 64 + lane) * 8);
    #pragma unroll
    for (int rt = 0; rt < RT; rt++) {
      short8 a = *(const short8*)(&Zt[(rt * 16 + colq) * SK + ks * 32 + quad * 8]);
      acc[rt][0] = __builtin_amdgcn_mfma_f32_16x16x32_bf16(a, bfr0, acc[rt][0], 0, 0, 0);
      acc[rt][1] = __builtin_amdgcn_mfma_f32_16x16x32_bf16(a, bfr1, acc[rt][1], 0, 0, 0);
    }
  }
  #pragma unroll
  for (int c = 0; c < 2; c++) {
    int col = wave * 32 + c * 16 + colq;
    float bv = b2f(fuB1[col]);
    #pragma unroll
    for (int rt = 0; rt < RT; rt++)
      #pragma unroll
      for (int r = 0; r < 4; r++)
        Zt[(rt * 16 + quad * 4 + r) * SK + 128 + col] =
            __float2bfloat16(fmaxf(acc[rt][c][r] + bv, 0.f));
  }
  __syncthreads();

  #pragma unroll
  for (int rt = 0; rt < RT; rt++)
    #pragma unroll
    for (int c = 0; c < 2; c++) acc[rt][c] = (floatx4){0.f, 0.f, 0.f, 0.f};
  #pragma unroll
  for (int ks = 0; ks < 4; ks++) {
    short8 bfr0 = *(const short8*)(fuW2 + (((size_t)(wave * 2 + 0) * 4 + ks) * 64 + lane) * 8);
    short8 bfr1 = *(const short8*)(fuW2 + (((size_t)(wave * 2 + 1) * 4 + ks) * 64 + lane) * 8);
    #pragma unroll
    for (int rt = 0; rt < RT; rt++) {
      short8 a = *(const short8*)(&Zt[(rt * 16 + colq) * SK + 128 + ks * 32 + quad * 8]);
      acc[rt][0] = __builtin_amdgcn_mfma_f32_16x16x32_bf16(a, bfr0, acc[rt][0], 0, 0, 0);
      acc[rt][1] = __builtin_amdgcn_mfma_f32_16x16x32_bf16(a, bfr1, acc[rt][1], 0, 0, 0);
    }
  }
  #pragma unroll
  for (int c = 0; c < 2; c++) {
    int col = wave * 32 + c * 16 + colq;
    float bv = b2f(fuB2[col]);
    #pragma unroll
    for (int rt = 0; rt < RT; rt++)
      #pragma unroll
      for (int r = 0; r < 4; r++) {
        int grow = row0 + rt * 16 + quad * 4 + r;
        if (grow < M) outp[(size_t)grow * HDIM + col] = __float2bfloat16(acc[rt][c][r] + bv);
      }
  }
}

// -------------------------------------------------- typed enc/dec (type-sorted MFMA)
template<int KS1, bool DEC>
__global__ void __launch_bounds__(256) typed_kernel(
    const bf16* __restrict__ in0, const bf16* __restrict__ in1,
    const int* __restrict__ perm, const int* __restrict__ ts, const int* __restrict__ flagp,
    const bf16* __restrict__ W1p, int w1s, const bf16* __restrict__ b1v, int b1s,
    const bf16* __restrict__ W2p, int w2s, const bf16* __restrict__ b2v, int b2s,
    void* __restrict__ outp) {
  constexpr int BM = 64, RT = 4;
  constexpr int SK = KS1 * 32 + 8;
  constexpr int HS = 136;
  int t = blockIdx.y;
  int rs = ts[t], re = ts[t + 1];
  int row0 = rs + blockIdx.x * BM;
  if (row0 >= re) return;
  __shared__ bf16 Zt[BM * SK];
  __shared__ bf16 Hid[BM * HS];
  __shared__ int gIdx[BM];
  const int tid = threadIdx.x;
  const int lane = tid & 63, wave = tid >> 6, colq = lane & 15, quad = lane >> 4;
  for (int i = tid; i < BM; i += 256) gIdx[i] = (row0 + i < re) ? perm[row0 + i] : -1;
  __syncthreads();
  if (DEC) {
    int row = tid >> 2, sub = tid & 3;
    int g = gIdx[row];
    #pragma unroll
    for (int j = 0; j < 4; j++) {
      int seg = j * 4 + sub;
      uint4 v = {0u, 0u, 0u, 0u};
      if (g >= 0) v = *(const uint4*)(in0 + (size_t)g * HDIM + seg * 8);
      *(uint4*)(&Zt[row * SK + seg * 8]) = v;
    }
  } else {
    for (int i = tid; i < BM * 32; i += 256) {
      int row = i >> 5, k = i & 31;
      int g = gIdx[row];
      bf16 v = __float2bfloat16(0.f);
      if (g >= 0 && k < 14) v = (k < 6) ? in0[(size_t)g * 6 + k] : in1[(size_t)g * 8 + (k - 6)];
      Zt[row * SK + k] = v;
    }
  }
  __syncthreads();

  const bf16* W1t = W1p + (size_t)t * w1s;
  const bf16* W2t = W2p + (size_t)t * w2s;
  floatx4 acc[RT][2];
  #pragma unroll
  for (int rt = 0; rt < RT; rt++)
    #pragma unroll
    for (int c = 0; c < 2; c++) acc[rt][c] = (floatx4){0.f, 0.f, 0.f, 0.f};
  #pragma unroll
  for (int ks = 0; ks < KS1; ks++) {
    short8 bfr0 = *(const short8*)(W1t + (((size_t)(wave * 2 + 0) * KS1 + ks) * 64 + lane) * 8);
    short8 bfr1 = *(const short8*)(W1t + (((size_t)(wave * 2 + 1) * KS1 + ks) * 64 + lane) * 8);
    #pragma unroll
    for (int rt = 0; rt < RT; rt++) {
      short8 a = *(const short8*)(&Zt[(rt * 16 + colq) * SK + ks * 32 + quad * 8]);
      acc[rt][0] = __builtin_amdgcn_mfma_f32_16x16x32_bf16(a, bfr0, acc[rt][0], 0, 0, 0);
      acc[rt][1] = __builtin_amdgcn_mfma_f32_16x16x32_bf16(a, bfr1, acc[rt][1], 0, 0, 0);
    }
  }
  #pragma unroll
  for (int c = 0; c < 2; c++) {
    int col = wave * 32 + c * 16 + colq;
    float bv = b2f(b1v[t * b1s + col]);
    #pragma unroll
    for (int rt = 0; rt < RT; rt++)
      #pragma unroll
      for (int r = 0; r < 4; r++) {
        float v = acc[rt][c][r] + bv;
        Hid[(rt * 16 + quad * 4 + r) * HS + col] = __float2bfloat16(fmaxf(v, 0.f));
      }
  }
  __syncthreads();

  floatx4 acc2[RT][2];
  #pragma unroll
  for (int rt = 0; rt < RT; rt++)
    #pragma unroll
    for (int c = 0; c < 2; c++) acc2[rt][c] = (floatx4){0.f, 0.f, 0.f, 0.f};
  #pragma unroll
  for (int ks = 0; ks < 4; ks++) {
    short8 bfr0 = *(const short8*)(W2t + (((size_t)(wave * 2 + 0) * 4 + ks) * 64 + lane) * 8);
    short8 bfr1 = *(const short8*)(W2t + (((size_t)(wave * 2 + 1) * 4 + ks) * 64 + lane) * 8);
    #pragma unroll
    for (int rt = 0; rt < RT; rt++) {
      short8 a = *(const short8*)(&Hid[(rt * 16 + colq) * HS + ks * 32 + quad * 8]);
      acc2[rt][0] = __builtin_amdgcn_mfma_f32_16x16x32_bf16(a, bfr0, acc2[rt][0], 0, 0, 0);
      acc2[rt][1] = __builtin_amdgcn_mfma_f32_16x16x32_bf16(a, bfr1, acc2[rt][1], 0, 0, 0);
    }
  }
  if (DEC) {
    if (wave == 0 && colq < 4) {
      int isBf = flagp[0];
      float bv = b2f(b2v[t * b2s + colq]);
      #pragma unroll
      for (int rt = 0; rt < RT; rt++)
        #pragma unroll
        for (int r = 0; r < 4; r++) {
          int g = gIdx[rt * 16 + quad * 4 + r];
          if (g >= 0) {
            float v = acc2[rt][0][r] + bv;
            if (isBf) ((bf16*)outp)[(size_t)g * 4 + colq] = __float2bfloat16(v);
            else      ((float*)outp)[(size_t)g * 4 + colq] = v;
          }
        }
    }
  } else {
    #pragma unroll
    for (int c = 0; c < 2; c++) {
      int col = wave * 32 + c * 16 + colq;
      float bv = b2f(b2v[t * b2s + col]);
      #pragma unroll
      for (int rt = 0; rt < RT; rt++)
        #pragma unroll
        for (int r = 0; r < 4; r++) {
          int g = gIdx[rt * 16 + quad * 4 + r];
          if (g >= 0) ((bf16*)outp)[(size_t)g * HDIM + col] = __float2bfloat16(acc2[rt][c][r] + bv);
        }
    }
  }
}

// -------------------------------------------------- edge-encoder MLP (attr4 path)
template<int BM>
__global__ void __launch_bounds__(256) ee_kernel(
    const bf16* __restrict__ p0, const int* __restrict__ idx0,
    const bf16* __restrict__ W1p, const bf16* __restrict__ b1v,
    const bf16* __restrict__ W2p, const bf16* __restrict__ b2v,
    bf16* __restrict__ outp, int M) {
  constexpr int RT = BM / 16;
  constexpr int SK = 136;
  __shared__ bf16 Zt[BM * SK];
  const int tid = threadIdx.x;
  const int lane = tid & 63, wave = tid >> 6, colq = lane & 15, quad = lane >> 4;
  const int row0 = blockIdx.x * BM;

  for (int i = tid; i < BM * 4; i += 256) {
    int row = i >> 2, seg = i & 3;
    int gr = row0 + row;
    uint4 val = {0u, 0u, 0u, 0u};
    if (seg == 0 && gr < M) {
      int g = idx0 ? idx0[gr] : gr;
      uint2 v = *(const uint2*)(p0 + (size_t)g * 4);
      val.x = v.x; val.y = v.y;
    }
    *(uint4*)(&Zt[row * SK + seg * 8]) = val;
  }
  __syncthreads();

  floatx4 acc[RT][2];
  #pragma unroll
  for (int rt = 0; rt < RT; rt++)
    #pragma unroll
    for (int c = 0; c < 2; c++) acc[rt][c] = (floatx4){0.f, 0.f, 0.f, 0.f};
  {
    short8 bfr0 = *(const short8*)(W1p + (((size_t)(wave * 2 + 0)) * 64 + lane) * 8);
    short8 bfr1 = *(const short8*)(W1p + (((size_t)(wave * 2 + 1)) * 64 + lane) * 8);
    #pragma unroll
    for (int rt = 0; rt < RT; rt++) {
      short8 a = *(const short8*)(&Zt[(rt * 16 + colq) * SK + quad * 8]);
      acc[rt][0] = __builtin_amdgcn_mfma_f32_16x16x32_bf16(a, bfr0, acc[rt][0], 0, 0, 0);
      acc[rt][1] = __builtin_amdgcn_mfma_f32_16x16x32_bf16(a, bfr1, acc[rt][1], 0, 0, 0);
    }
  }
  __syncthreads();
  #pragma unroll
  for (int c = 0; c < 2; c++) {
    int col = wave * 32 + c * 16 + colq;
    float bv = b2f(b1v[col]);
    #pragma unroll
    for (int rt = 0; rt < RT; rt++)
      #pragma unroll
      for (int r = 0; r < 4; r++)
        Zt[(rt * 16 + quad * 4 + r) * SK + col] =
            __float2bfloat16(fmaxf(acc[rt][c][r] + bv, 0.f));
  }
  __syncthreads();

  floatx4 acc2[RT][2];
  #pragma unroll
  for (int rt = 0; rt < RT; rt++)
    #pragma unroll
    for (int c = 0; c < 2; c++) acc2[rt][c] = (floatx4){0.f, 0.f, 0.f, 0.f};
  #pragma unroll
  for (int ks = 0; ks < 4; ks++) {
    short8 bfr0 = *(const short8*)(W2p + (((size_t)(wave * 2 + 0) * 4 + ks) * 64 + lane) * 8);
    short8 bfr1 = *(const short8*)(W2p + (((size_t)(wave * 2 + 1) * 4 + ks) * 64 + lane) * 8);
    #pragma unroll
    for (int rt = 0; rt < RT; rt++) {
      short8 a = *(const short8*)(&Zt[(rt * 16 + colq) * SK + ks * 32 + quad * 8]);
      acc2[rt][0] = __builtin_amdgcn_mfma_f32_16x16x32_bf16(a, bfr0, acc2[rt][0], 0, 0, 0);
      acc2[rt][1] = __builtin_amdgcn_mfma_f32_16x16x32_bf16(a, bfr1, acc2[rt][1], 0, 0, 0);
    }
  }
  #pragma unroll
  for (int c = 0; c < 2; c++) {
    int col = wave * 32 + c * 16 + colq;
    float bv = b2f(b2v[col]);
    #pragma unroll
    for (int rt = 0; rt < RT; rt++)
      #pragma unroll
      for (int r = 0; r < 4; r++) {
        int grow = row0 + rt * 16 + quad * 4 + r;
        if (grow < M)
          outp[(size_t)grow * HDIM + col] = __float2bfloat16(acc2[rt][c][r] + bv);
      }
  }
}

// ---------------------------------------------------------------- launcher
extern "C" void kernel_launch(void* const* d_in, const int* in_sizes, int n_in,
                              void* d_out, int out_size, void* d_ws, size_t ws_size,
                              hipStream_t stream) {
  const int* edge_index = (const int*)d_in[27];
  const int* node_types = (const int*)d_in[28];
  const int N = in_sizes[28];
  const int E = in_sizes[2] / 4;
  const int L = in_sizes[12] / HDIM;
  const int* srcI = edge_index;
  const int* dstI = edge_index + E;

  CanonDesc cd;
  int total = 0;
  for (int i = 0; i < NCANON; i++) { cd.src[i] = d_in[i]; cd.prefix[i] = total; total += in_sizes[i]; }
  cd.prefix[NCANON] = total;

  char* wsb = (char*)d_ws;
  size_t off = 0;
  auto alloc = [&](size_t bytes) -> void* {
    void* p = wsb + off;
    off += (bytes + 255) & ~(size_t)255;
    return p;
  };
  int*  flag      = (int*)alloc(256);
  bf16* arena     = (bf16*)alloc((size_t)total * 2);
  bf16* h_nodes   = (bf16*)alloc((size_t)N * HDIM * 2);
  bf16* h_edges   = (bf16*)alloc((size_t)E * HDIM * 2);
  float* m_node   = (float*)alloc((size_t)N * HDIM * 4);
  bf16* ysrcb     = (bf16*)alloc((size_t)N * HDIM * 2);
  bf16* ydstb     = (bf16*)alloc((size_t)N * HDIM * 2);
  int* counts     = (int*)alloc((size_t)N * 4);
  int* cursor     = (int*)alloc((size_t)N * 4);
  int* row_start  = (int*)alloc((size_t)(N + 1) * 4);
  int* bsum       = (int*)alloc(260 * 4);
  int* sortedE    = (int*)alloc((size_t)E * 4);
  int* srcS       = (int*)alloc((size_t)E * 4);
  int* dstS       = (int*)alloc((size_t)E * 4);
  int* tsArr      = (int*)alloc(64);
  int* permT      = (int*)alloc((size_t)N * 4);
  bf16* eeW1p  = (bf16*)alloc(4096 * 2);
  bf16* eeW2p  = (bf16*)alloc(16384 * 2);
  bf16* encW1p = (bf16*)alloc(3 * 4096 * 2);
  bf16* encW2p = (bf16*)alloc(3 * 16384 * 2);
  bf16* decW1p = (bf16*)alloc(3 * 16384 * 2);
  bf16* decW2p = (bf16*)alloc(3 * 16384 * 2);
  bf16* euW1a  = (bf16*)alloc((size_t)L * 16384 * 2);
  bf16* euW1b  = (bf16*)alloc((size_t)L * 16384 * 2);
  bf16* euW1c  = (bf16*)alloc((size_t)L * 16384 * 2);
  bf16* euW2p  = (bf16*)alloc((size_t)L * 16384 * 2);
  bf16* nuW1p  = (bf16*)alloc((size_t)L * 32768 * 2);
  bf16* nuW2p  = (bf16*)alloc((size_t)L * 16384 * 2);
  bf16* fuW1p  = (bf16*)alloc((size_t)L * 16384 * 2);
  bf16* fuW2p  = (bf16*)alloc((size_t)L * 16384 * 2);

  const bf16* cX     = arena + cd.prefix[0];
  const bf16* cPE    = arena + cd.prefix[1];
  const bf16* cEA    = arena + cd.prefix[2];
  const bf16* cEncW1 = arena + cd.prefix[3];
  const bf16* cEncB1 = arena + cd.prefix[4];
  const bf16* cEncW2 = arena + cd.prefix[5];
  const bf16* cEncB2 = arena + cd.prefix[6];
  const bf16* cEeW1  = arena + cd.prefix[7];
  const bf16* cEeB1  = arena + cd.prefix[8];
  const bf16* cEeW2  = arena + cd.prefix[9];
  const bf16* cEeB2  = arena + cd.prefix[10];
  const bf16* cEuW1  = arena + cd.prefix[11];
  const bf16* cEuB1  = arena + cd.prefix[12];
  const bf16* cEuW2  = arena + cd.prefix[13];
  const bf16* cEuB2  = arena + cd.prefix[14];
  const bf16* cNuW1  = arena + cd.prefix[15];
  const bf16* cNuB1  = arena + cd.prefix[16];
  const bf16* cNuW2  = arena + cd.prefix[17];
  const bf16* cNuB2  = arena + cd.prefix[18];
  const bf16* cFuW1  = arena + cd.prefix[19];
  const bf16* cFuB1  = arena + cd.prefix[20];
  const bf16* cFuW2  = arena + cd.prefix[21];
  const bf16* cFuB2  = arena + cd.prefix[22];
  const bf16* cDecW1 = arena + cd.prefix[23];
  const bf16* cDecB1 = arena + cd.prefix[24];
  const bf16* cDecW2 = arena + cd.prefix[25];
  const bf16* cDecB2 = arena + cd.prefix[26];

  canon_kernel<<<(total + 255) / 256, 256, 0, stream>>>(
      cd, (const unsigned short*)d_in[0], flag, arena, total);

  hipMemsetAsync(counts, 0, (size_t)N * 4, stream);
  hipMemsetAsync(cursor, 0, (size_t)N * 4, stream);

  PackJobs PJ;
  int nj = 0;
  PJ.j[nj++] = {cEeW1, eeW1p, 4, 1, 128};
  PJ.j[nj++] = {cEeW2, eeW2p, 128, 4, 128};
  for (int l = 0; l < L; l++) {
    const bf16* w1 = cEuW1 + (size_t)l * 384 * HDIM;
    PJ.j[nj++] = {w1,                 euW1a + (size_t)l * 16384, 128, 4, 128};
    PJ.j[nj++] = {w1 + 128 * HDIM,    euW1b + (size_t)l * 16384, 128, 4, 128};
    PJ.j[nj++] = {w1 + 256 * HDIM,    euW1c + (size_t)l * 16384, 128, 4, 128};
    PJ.j[nj++] = {cEuW2 + (size_t)l * HDIM * HDIM, euW2p + (size_t)l * 16384, 128, 4, 128};
    PJ.j[nj++] = {cNuW1 + (size_t)l * 256 * HDIM,  nuW1p + (size_t)l * 32768, 256, 8, 128};
    PJ.j[nj++] = {cNuW2 + (size_t)l * HDIM * HDIM, nuW2p + (size_t)l * 16384, 128, 4, 128};
    PJ.j[nj++] = {cFuW1 + (size_t)l * HDIM * HDIM, fuW1p + (size_t)l * 16384, 128, 4, 128};
    PJ.j[nj++] = {cFuW2 + (size_t)l * HDIM * HDIM, fuW2p + (size_t)l * 16384, 128, 4, 128};
  }
  for (int t = 0; t < 3; t++) {
    PJ.j[nj++] = {cEncW1 + (size_t)t * 14 * HDIM,   encW1p + (size_t)t * 4096, 14, 1, 128};
    PJ.j[nj++] = {cEncW2 + (size_t)t * HDIM * HDIM, encW2p + (size_t)t * 16384, 128, 4, 128};
    PJ.j[nj++] = {cDecW1 + (size_t)t * HDIM * HDIM, decW1p + (size_t)t * 16384, 128, 4, 128};
    PJ.j[nj++] = {cDecW2 + (size_t)t * HDIM * 4,    decW2p + (size_t)t * 16384, 128, 4, 4};
  }
  pack_all_kernel<<<dim3(16, nj), 256, 0, stream>>>(PJ);

  // CSR (dst-sorted edges)
  int nb = (N + 255) / 256;
  hist_kernel<<<(E + 255) / 256, 256, 0, stream>>>(dstI, counts, E);
  scan1_kernel<<<nb, 256, 0, stream>>>(counts, bsum, N);
  scan2_kernel<<<1, 64, 0, stream>>>(bsum, nb);
  scan3_kernel<<<nb, 256, 0, stream>>>(counts, bsum, row_start, N, nb);
  scatter_kernel<<<(E + 255) / 256, 256, 0, stream>>>(srcI, dstI, row_start, cursor,
                                                      sortedE, srcS, dstS, E);
  tsort_kernel<<<1, 1024, 0, stream>>>(node_types, tsArr, permT, N);

  int ngrid64 = (N + 63) / 64;
  typed_kernel<1, false><<<dim3(ngrid64, 3), 256, 0, stream>>>(
      cX, cPE, permT, tsArr, flag, encW1p, 4096, cEncB1, HDIM,
      encW2p, 16384, cEncB2, HDIM, h_nodes);

  int egrid32  = (E + 31) / 32;
  int egrid128 = (E + 127) / 128;

  ee_kernel<128><<<egrid128, 256, 0, stream>>>(
      cEA, sortedE, eeW1p, cEeB1, eeW2p, cEeB2, h_edges, E);

  for (int l = 0; l < L; l++) {
    ygemm_kernel<<<dim3(ngrid64, 2), 256, 0, stream>>>(
        h_nodes, euW1a + (size_t)l * 16384, euW1b + (size_t)l * 16384, ysrcb, ydstb, m_node, N);
    if (l + 1 < L) {
      eu_kernel<32, true><<<egrid32, 256, 0, stream>>>(
          h_edges, ysrcb, ydstb, srcS, dstS,
          euW1c + (size_t)l * 16384, cEuB1 + l * HDIM,
          euW2p + (size_t)l * 16384, cEuB2 + l * HDIM, h_edges, m_node, E);
    } else {
      eu_kernel<32, false><<<egrid32, 256, 0, stream>>>(   // last layer: h_edges dead after agg
          h_edges, ysrcb, ydstb, srcS, dstS,
          euW1c + (size_t)l * 16384, cEuB1 + l * HDIM,
          euW2p + (size_t)l * 16384, cEuB2 + l * HDIM, h_edges, m_node, E);
    }
    node_kernel<<<ngrid64, 256, 0, stream>>>(
        h_nodes, m_node,
        nuW1p + (size_t)l * 32768, cNuB1 + l * HDIM,
        nuW2p + (size_t)l * 16384, cNuB2 + l * HDIM,
        fuW1p + (size_t)l * 16384, cFuB1 + l * HDIM,
        fuW2p + (size_t)l * 16384, cFuB2 + l * HDIM, h_nodes, N);
  }

  typed_kernel<4, true><<<dim3(ngrid64, 3), 256, 0, stream>>>(
      h_nodes, nullptr, permT, tsArr, flag, decW1p, 16384, cDecB1, HDIM,
      decW2p, 16384, cDecB2, 4, d_out);
  (void)n_in; (void)ws_size;
}

// Round 10
// 496.584 us; speedup vs baseline: 1.1925x; 1.1925x over previous
//
#include <hip/hip_runtime.h>
#include <hip/hip_bf16.h>

typedef __hip_bfloat16 bf16;
typedef __attribute__((ext_vector_type(8))) short short8;   // 8 bf16 frag
typedef __attribute__((ext_vector_type(4))) float floatx4;  // MFMA C/D frag

#define HDIM 128
#define NCANON 27

__device__ __forceinline__ float b2f(bf16 v) { return __bfloat162float(v); }
__device__ __forceinline__ float s2f(short s) {
  return __uint_as_float(((unsigned int)(unsigned short)s) << 16);
}
__device__ __forceinline__ short f2s(float f) {
  return (short)__bfloat16_as_ushort(__float2bfloat16(f));
}

struct CanonDesc {
  const void* src[NCANON];
  int prefix[NCANON + 1];
};

// ---- canon with inlined dtype detect (block 0 publishes flag for the decoder)
__global__ void canon_kernel(CanonDesc d, const unsigned short* __restrict__ xraw,
                             int* __restrict__ flagOut, bf16* __restrict__ out, int total) {
  __shared__ int sflag;
  int tid = threadIdx.x;
  if (tid < 64) {
    unsigned short u = xraw[2 * tid];
    int e = (u >> 7) & 0xFF;
    int ok = (u == 0) || (e >= 100 && e <= 140);
    unsigned long long m = __ballot(ok);
    if (tid == 0) sflag = (__popcll(m) >= 48) ? 1 : 0;
  }
  __syncthreads();
  int isBf = sflag;
  if (blockIdx.x == 0 && tid == 0) flagOut[0] = isBf;
  int t = blockIdx.x * 256 + tid;
  if (t >= total) return;
  int lo = 0, hi = NCANON;
  while (lo + 1 < hi) { int mid = (lo + hi) >> 1; if (d.prefix[mid] <= t) lo = mid; else hi = mid; }
  int off = t - d.prefix[lo];
  out[t] = isBf ? ((const bf16*)d.src[lo])[off]
                : __float2bfloat16(((const float*)d.src[lo])[off]);
}

// ---------------------------------------------------------------- CSR build
__global__ void hist_kernel(const int* __restrict__ dst, int* __restrict__ cnt, int E) {
  int e = blockIdx.x * 256 + threadIdx.x;
  if (e < E) atomicAdd(&cnt[dst[e]], 1);
}

__global__ void scan1_kernel(const int* __restrict__ cnt, int* __restrict__ bsum, int n) {
  int tid = threadIdx.x, lane = tid & 63, wave = tid >> 6;
  int i = blockIdx.x * 256 + tid;
  int v = (i < n) ? cnt[i] : 0;
  #pragma unroll
  for (int d = 32; d; d >>= 1) v += __shfl_down(v, d);
  __shared__ int ws[4];
  if (lane == 0) ws[wave] = v;
  __syncthreads();
  if (tid == 0) bsum[blockIdx.x] = ws[0] + ws[1] + ws[2] + ws[3];
}

__global__ void scan2_kernel(int* __restrict__ bsum, int nb) {   // nb <= 128; 64 threads
  int lane = threadIdx.x;
  int a0 = (lane < nb) ? bsum[lane] : 0;
  int b0 = (64 + lane < nb) ? bsum[64 + lane] : 0;
  int a = a0, b = b0;
  #pragma unroll
  for (int d = 1; d < 64; d <<= 1) { int t = __shfl_up(a, d); if (lane >= d) a += t; }
  int totA = __shfl(a, 63);
  #pragma unroll
  for (int d = 1; d < 64; d <<= 1) { int t = __shfl_up(b, d); if (lane >= d) b += t; }
  int totB = __shfl(b, 63);
  if (lane < nb) bsum[lane] = a - a0;
  if (64 + lane < nb) bsum[64 + lane] = b - b0 + totA;
  if (lane == 0) bsum[nb] = totA + totB;
}

__global__ void scan3_kernel(const int* __restrict__ cnt, const int* __restrict__ bsum,
                             int* __restrict__ row_start, int n, int nb) {
  __shared__ int sh[256];
  int tid = threadIdx.x;
  int i = blockIdx.x * 256 + tid;
  int v = (i < n) ? cnt[i] : 0;
  sh[tid] = v;
  __syncthreads();
  #pragma unroll
  for (int off = 1; off < 256; off <<= 1) {
    int t = (tid >= off) ? sh[tid - off] : 0;
    __syncthreads();
    sh[tid] += t;
    __syncthreads();
  }
  if (i < n) row_start[i] = bsum[blockIdx.x] + sh[tid] - v;
  if (blockIdx.x == 0 && tid == 0) row_start[n] = bsum[nb];
}

__global__ void scatter_kernel(const int* __restrict__ src, const int* __restrict__ dst,
                               const int* __restrict__ row_start, int* __restrict__ cursor,
                               int* __restrict__ sortedE, int* __restrict__ srcS,
                               int* __restrict__ dstS, int E) {
  int e = blockIdx.x * 256 + threadIdx.x;
  if (e < E) {
    int d = dst[e];
    int pos = row_start[d] + atomicAdd(&cursor[d], 1);
    sortedE[pos] = e;
    srcS[pos] = src[e];
    dstS[pos] = d;
  }
}

// --------- type permutation: single-block atomic-free stable counting sort
__global__ void __launch_bounds__(1024) tsort_kernel(const int* __restrict__ types,
                                                     int* __restrict__ ts,
                                                     int* __restrict__ perm, int n) {
  __shared__ int wc[16][3];
  __shared__ int base[3];
  int tid = threadIdx.x, lane = tid & 63, wave = tid >> 6;
  int c0 = 0, c1 = 0, c2 = 0;
  for (int i = tid; i < n; i += 1024) {
    int t = types[i];
    c0 += (t == 0); c1 += (t == 1); c2 += (t == 2);
  }
  #pragma unroll
  for (int d = 32; d; d >>= 1) {
    c0 += __shfl_down(c0, d); c1 += __shfl_down(c1, d); c2 += __shfl_down(c2, d);
  }
  if (lane == 0) { wc[wave][0] = c0; wc[wave][1] = c1; wc[wave][2] = c2; }
  __syncthreads();
  if (tid == 0) {
    int t0 = 0, t1 = 0;
    for (int w = 0; w < 16; w++) { t0 += wc[w][0]; t1 += wc[w][1]; }
    ts[0] = 0; ts[1] = t0; ts[2] = t0 + t1; ts[3] = n;
    base[0] = 0; base[1] = t0; base[2] = t0 + t1;
  }
  __syncthreads();
  for (int i0 = 0; i0 < n; i0 += 1024) {
    int i = i0 + tid;
    int t = (i < n) ? types[i] : -1;
    unsigned long long m0 = __ballot(t == 0);
    unsigned long long m1 = __ballot(t == 1);
    unsigned long long m2 = __ballot(t == 2);
    if (lane == 0) { wc[wave][0] = __popcll(m0); wc[wave][1] = __popcll(m1); wc[wave][2] = __popcll(m2); }
    __syncthreads();
    if (i < n) {
      unsigned long long mt = (t == 0) ? m0 : ((t == 1) ? m1 : m2);
      unsigned long long below = (lane == 0) ? 0ull : ((1ull << lane) - 1ull);
      int r = __popcll(mt & below);
      int woff = 0;
      for (int w = 0; w < wave; w++) woff += wc[w][t];
      perm[base[t] + woff + r] = i;
    }
    __syncthreads();
    if (tid == 0) {
      int a0 = 0, a1 = 0, a2 = 0;
      for (int w = 0; w < 16; w++) { a0 += wc[w][0]; a1 += wc[w][1]; a2 += wc[w][2]; }
      base[0] += a0; base[1] += a1; base[2] += a2;
    }
    __syncthreads();
  }
}

// -------------------------------------------------- fused weight pre-pack (B-frag order)
struct PackJob { const bf16* src; bf16* dst; int Ksrc; int KS; int srcCols; };
struct PackJobs { PackJob j[40]; };

__global__ void pack_all_kernel(PackJobs J) {
  PackJob job = J.j[blockIdx.y];
  int idx = blockIdx.x * 256 + threadIdx.x;
  int total = 8 * job.KS * 64;
  if (idx >= total) return;
  int lane = idx & 63;
  int ks = (idx >> 6) % job.KS;
  int ct = idx / (64 * job.KS);
  bf16* o = job.dst + (size_t)idx * 8;
  int ncol = ct * 16 + (lane & 15);
  int kb = ks * 32 + ((lane >> 4) & 3) * 8;
  #pragma unroll
  for (int jj = 0; jj < 8; jj++) {
    int k = kb + jj;
    o[jj] = (k < job.Ksrc && ncol < job.srcCols)
              ? job.src[(size_t)k * job.srcCols + ncol] : __float2bfloat16(0.f);
  }
}

// ------------- per-node Y = h @ W1a / W1b (bf16 out) + zero m_node (y==0 blocks)
__global__ void __launch_bounds__(256) ygemm_kernel(
    const bf16* __restrict__ X,
    const bf16* __restrict__ WpA, const bf16* __restrict__ WpB,
    bf16* __restrict__ outA, bf16* __restrict__ outB,
    float* __restrict__ mnode, int M) {
  const bf16* Wp = blockIdx.y ? WpB : WpA;
  bf16* outp = blockIdx.y ? outB : outA;
  constexpr int BM = 64, RT = 4, SK = 136;
  __shared__ bf16 Zt[BM * SK];
  const int tid = threadIdx.x;
  const int lane = tid & 63, wave = tid >> 6, colq = lane & 15, quad = lane >> 4;
  const int row0 = blockIdx.x * BM;
  if (blockIdx.y == 0) {                    // zero this tile's m_node rows
    float4 z = {0.f, 0.f, 0.f, 0.f};
    for (int i = tid; i < BM * 32; i += 256) {
      int row = i >> 5, q = i & 31;
      int gr = row0 + row;
      if (gr < M) *(float4*)(mnode + (size_t)gr * HDIM + q * 4) = z;
    }
  }
  {
    int row = tid >> 2, sub = tid & 3;
    int gr = row0 + row;
    bool ok = gr < M;
    #pragma unroll
    for (int j = 0; j < 4; j++) {
      int seg = j * 4 + sub;
      uint4 v = {0u, 0u, 0u, 0u};
      if (ok) v = *(const uint4*)(X + (size_t)gr * HDIM + seg * 8);
      *(uint4*)(&Zt[row * SK + seg * 8]) = v;
    }
  }
  __syncthreads();
  floatx4 acc[RT][2];
  #pragma unroll
  for (int rt = 0; rt < RT; rt++)
    #pragma unroll
    for (int c = 0; c < 2; c++) acc[rt][c] = (floatx4){0.f, 0.f, 0.f, 0.f};
  #pragma unroll
  for (int ks = 0; ks < 4; ks++) {
    short8 bfr0 = *(const short8*)(Wp + (((size_t)(wave * 2 + 0) * 4 + ks) * 64 + lane) * 8);
    short8 bfr1 = *(const short8*)(Wp + (((size_t)(wave * 2 + 1) * 4 + ks) * 64 + lane) * 8);
    #pragma unroll
    for (int rt = 0; rt < RT; rt++) {
      short8 a = *(const short8*)(&Zt[(rt * 16 + colq) * SK + ks * 32 + quad * 8]);
      acc[rt][0] = __builtin_amdgcn_mfma_f32_16x16x32_bf16(a, bfr0, acc[rt][0], 0, 0, 0);
      acc[rt][1] = __builtin_amdgcn_mfma_f32_16x16x32_bf16(a, bfr1, acc[rt][1], 0, 0, 0);
    }
  }
  #pragma unroll
  for (int c = 0; c < 2; c++) {
    int col = wave * 32 + c * 16 + colq;
    #pragma unroll
    for (int rt = 0; rt < RT; rt++)
      #pragma unroll
      for (int r = 0; r < 4; r++) {
        int grow = row0 + rt * 16 + quad * 4 + r;
        if (grow < M) outp[(size_t)grow * HDIM + col] = __float2bfloat16(acc[rt][c][r]);
      }
  }
}

// ----------------------- edge-update + fused dst-segment aggregation
// out = h_e_old + (ReLU(h_e @ W1c + ysum + b1) @ W2 + b2); m_node[dst] += out (f32)
// Zt part0 = ysum bf16 (16B short8 gathers; becomes Hid in-place), part1 = h_e
// (becomes out in-place). Edges dst-sorted; split segmented sums; boundary atomics.
template<int BM, bool WRITE_HE>
__global__ void __launch_bounds__(256) eu_kernel(
    const bf16* __restrict__ he, const bf16* __restrict__ ysrc, const bf16* __restrict__ ydst,
    const int* __restrict__ srcS, const int* __restrict__ dstS,
    const bf16* __restrict__ W1p, const bf16* __restrict__ b1v,
    const bf16* __restrict__ W2p, const bf16* __restrict__ b2v,
    bf16* __restrict__ outp, float* __restrict__ mnode, int M) {
  constexpr int RT = BM / 16;
  constexpr int SK = 264;
  __shared__ bf16 Zt[BM * SK];
  __shared__ int dstLds[BM];
  const int tid = threadIdx.x;
  const int lane = tid & 63, wave = tid >> 6, colq = lane & 15, quad = lane >> 4;
  const int row0 = blockIdx.x * BM;
  constexpr int TPR = 256 / BM;
  {
    int row = tid / TPR, sub = tid % TPR;
    int gr = row0 + row;
    bool ok = gr < M;
    int g0 = ok ? srcS[gr] : 0;
    int g1 = ok ? dstS[gr] : 0;
    if (sub == 0) dstLds[row] = ok ? g1 : -1;
    #pragma unroll
    for (int j = 0; j < 32 / TPR; j++) {
      int c = j * TPR + sub;
      int part = c >> 4, seg = c & 15;
      if (part == 0) {
        short8 o = {0, 0, 0, 0, 0, 0, 0, 0};
        if (ok) {
          short8 a = *(const short8*)(ysrc + (size_t)g0 * HDIM + seg * 8);
          short8 b = *(const short8*)(ydst + (size_t)g1 * HDIM + seg * 8);
          #pragma unroll
          for (int k = 0; k < 8; k++) o[k] = f2s(s2f(a[k]) + s2f(b[k]));
        }
        *(short8*)(&Zt[row * SK + seg * 8]) = o;
      } else {
        uint4 v = {0u, 0u, 0u, 0u};
        if (ok) v = *(const uint4*)(he + (size_t)gr * HDIM + seg * 8);
        *(uint4*)(&Zt[row * SK + 128 + seg * 8]) = v;
      }
    }
  }
  __syncthreads();

  floatx4 acc[RT][2];
  #pragma unroll
  for (int rt = 0; rt < RT; rt++)
    #pragma unroll
    for (int c = 0; c < 2; c++) acc[rt][c] = (floatx4){0.f, 0.f, 0.f, 0.f};
  #pragma unroll
  for (int ks = 0; ks < 4; ks++) {
    short8 bfr0 = *(const short8*)(W1p + (((size_t)(wave * 2 + 0) * 4 + ks) * 64 + lane) * 8);
    short8 bfr1 = *(const short8*)(W1p + (((size_t)(wave * 2 + 1) * 4 + ks) * 64 + lane) * 8);
    #pragma unroll
    for (int rt = 0; rt < RT; rt++) {
      short8 a = *(const short8*)(&Zt[(rt * 16 + colq) * SK + 128 + ks * 32 + quad * 8]);
      acc[rt][0] = __builtin_amdgcn_mfma_f32_16x16x32_bf16(a, bfr0, acc[rt][0], 0, 0, 0);
      acc[rt][1] = __builtin_amdgcn_mfma_f32_16x16x32_bf16(a, bfr1, acc[rt][1], 0, 0, 0);
    }
  }
  // GEMM1 epilogue: Hid = ReLU(acc + b1 + ysum), in place over part0
  #pragma unroll
  for (int c = 0; c < 2; c++) {
    int col = wave * 32 + c * 16 + colq;
    float bv = b2f(b1v[col]);
    #pragma unroll
    for (int rt = 0; rt < RT; rt++)
      #pragma unroll
      for (int r = 0; r < 4; r++) {
        int lrow = rt * 16 + quad * 4 + r;
        float v = acc[rt][c][r] + bv + b2f(Zt[lrow * SK + col]);
        Zt[lrow * SK + col] = __float2bfloat16(fmaxf(v, 0.f));
      }
  }
  __syncthreads();

  floatx4 acc2[RT][2];
  #pragma unroll
  for (int rt = 0; rt < RT; rt++)
    #pragma unroll
    for (int c = 0; c < 2; c++) acc2[rt][c] = (floatx4){0.f, 0.f, 0.f, 0.f};
  #pragma unroll
  for (int ks = 0; ks < 4; ks++) {
    short8 bfr0 = *(const short8*)(W2p + (((size_t)(wave * 2 + 0) * 4 + ks) * 64 + lane) * 8);
    short8 bfr1 = *(const short8*)(W2p + (((size_t)(wave * 2 + 1) * 4 + ks) * 64 + lane) * 8);
    #pragma unroll
    for (int rt = 0; rt < RT; rt++) {
      short8 a = *(const short8*)(&Zt[(rt * 16 + colq) * SK + ks * 32 + quad * 8]);
      acc2[rt][0] = __builtin_amdgcn_mfma_f32_16x16x32_bf16(a, bfr0, acc2[rt][0], 0, 0, 0);
      acc2[rt][1] = __builtin_amdgcn_mfma_f32_16x16x32_bf16(a, bfr1, acc2[rt][1], 0, 0, 0);
    }
  }
  // GEMM2 epilogue: out = acc2 + b2 + h_e(part1); store to part1 (+ global unless last layer)
  #pragma unroll
  for (int c = 0; c < 2; c++) {
    int col = wave * 32 + c * 16 + colq;
    float bv = b2f(b2v[col]);
    #pragma unroll
    for (int rt = 0; rt < RT; rt++)
      #pragma unroll
      for (int r = 0; r < 4; r++) {
        int lrow = rt * 16 + quad * 4 + r;
        int grow = row0 + lrow;
        float v = acc2[rt][c][r] + bv + b2f(Zt[lrow * SK + 128 + col]);
        bf16 vb = __float2bfloat16(v);
        Zt[lrow * SK + 128 + col] = vb;
        if (WRITE_HE && grow < M) outp[(size_t)grow * HDIM + col] = vb;
      }
  }
  __syncthreads();

  // fused aggregation: two halves, 256 threads; boundary runs atomicAdd
  {
    int col = tid & 127;
    int half = tid >> 7;
    int rbeg = half * (BM / 2), rend = rbeg + (BM / 2);
    float s = 0.f;
    int runDst = dstLds[rbeg];
    bool touchStart = true;
    for (int r = rbeg; r < rend; r++) {
      int d = dstLds[r];
      if (d != runDst) {
        if (runDst >= 0) {
          float* mp = &mnode[(size_t)runDst * HDIM + col];
          if (touchStart) atomicAdd(mp, s); else *mp = s;
        }
        runDst = d; s = 0.f; touchStart = false;
      }
      s += b2f(Zt[r * SK + 128 + col]);
    }
    if (runDst >= 0) atomicAdd(&mnode[(size_t)runDst * HDIM + col], s);
  }
}

// ----------------------- fused node update + fusion MLP (nu + fu)
__global__ void __launch_bounds__(256) node_kernel(
    const bf16* __restrict__ h_nodes, const float* __restrict__ mnode,
    const bf16* __restrict__ nuW1, const bf16* __restrict__ nuB1,
    const bf16* __restrict__ nuW2, const bf16* __restrict__ nuB2,
    const bf16* __restrict__ fuW1, const bf16* __restrict__ fuB1,
    const bf16* __restrict__ fuW2, const bf16* __restrict__ fuB2,
    bf16* __restrict__ outp, int M) {
  constexpr int BM = 64, RT = 4, SK = 264;
  __shared__ bf16 Zt[BM * SK];
  const int tid = threadIdx.x;
  const int lane = tid & 63, wave = tid >> 6, colq = lane & 15, quad = lane >> 4;
  const int row0 = blockIdx.x * BM;
  {
    int row = tid >> 2, sub = tid & 3;
    int gr = row0 + row;
    bool ok = gr < M;
    #pragma unroll
    for (int j = 0; j < 8; j++) {
      int c = j * 4 + sub;
      int part = c >> 4, seg = c & 15;
      if (part == 0) {
        uint4 v = {0u, 0u, 0u, 0u};
        if (ok) v = *(const uint4*)(h_nodes + (size_t)gr * HDIM + seg * 8);
        *(uint4*)(&Zt[row * SK + seg * 8]) = v;
      } else {
        short8 o = {0, 0, 0, 0, 0, 0, 0, 0};
        if (ok) {
          const float* mp = mnode + (size_t)gr * HDIM + seg * 8;
          #pragma unroll
          for (int k = 0; k < 8; k++) o[k] = f2s(mp[k]);
        }
        *(short8*)(&Zt[row * SK + 128 + seg * 8]) = o;
      }
    }
  }
  __syncthreads();

  floatx4 acc[RT][2];
  #pragma unroll
  for (int rt = 0; rt < RT; rt++)
    #pragma unroll
    for (int c = 0; c < 2; c++) acc[rt][c] = (floatx4){0.f, 0.f, 0.f, 0.f};
  #pragma unroll
  for (int ks = 0; ks < 8; ks++) {
    short8 bfr0 = *(const short8*)(nuW1 + (((size_t)(wave * 2 + 0) * 8 + ks) * 64 + lane) * 8);
    short8 bfr1 = *(const short8*)(nuW1 + (((size_t)(wave * 2 + 1) * 8 + ks) * 64 + lane) * 8);
    #pragma unroll
    for (int rt = 0; rt < RT; rt++) {
      short8 a = *(const short8*)(&Zt[(rt * 16 + colq) * SK + ks * 32 + quad * 8]);
      acc[rt][0] = __builtin_amdgcn_mfma_f32_16x16x32_bf16(a, bfr0, acc[rt][0], 0, 0, 0);
      acc[rt][1] = __builtin_amdgcn_mfma_f32_16x16x32_bf16(a, bfr1, acc[rt][1], 0, 0, 0);
    }
  }
  __syncthreads();
  #pragma unroll
  for (int c = 0; c < 2; c++) {
    int col = wave * 32 + c * 16 + colq;
    float bv = b2f(nuB1[col]);
    #pragma unroll
    for (int rt = 0; rt < RT; rt++)
      #pragma unroll
      for (int r = 0; r < 4; r++)
        Zt[(rt * 16 + quad * 4 + r) * SK + 128 + col] =
            __float2bfloat16(fmaxf(acc[rt][c][r] + bv, 0.f));
  }
  __syncthreads();

  #pragma unroll
  for (int rt = 0; rt < RT; rt++)
    #pragma unroll
    for (int c = 0; c < 2; c++) acc[rt][c] = (floatx4){0.f, 0.f, 0.f, 0.f};
  #pragma unroll
  for (int ks = 0; ks < 4; ks++) {
    short8 bfr0 = *(const short8*)(nuW2 + (((size_t)(wave * 2 + 0) * 4 + ks) * 64 + lane) * 8);
    short8 bfr1 = *(const short8*)(nuW2 + (((size_t)(wave * 2 + 1) * 4 + ks) * 64 + lane) * 8);
    #pragma unroll
    for (int rt = 0; rt < RT; rt++) {
      short8 a = *(const short8*)(&Zt[(rt * 16 + colq) * SK + 128 + ks * 32 + quad * 8]);
      acc[rt][0] = __builtin_amdgcn_mfma_f32_16x16x32_bf16(a, bfr0, acc[rt][0], 0, 0, 0);
      acc[rt][1] = __builtin_amdgcn_mfma_f32_16x16x32_bf16(a, bfr1, acc[rt][1], 0, 0, 0);
    }
  }
  #pragma unroll
  for (int c = 0; c < 2; c++) {
    int col = wave * 32 + c * 16 + colq;
    float bv = b2f(nuB2[col]);
    #pragma unroll
    for (int rt = 0; rt < RT; rt++)
      #pragma unroll
      for (int r = 0; r < 4; r++) {
        int lrow = rt * 16 + quad * 4 + r;
        float v = acc[rt][c][r] + bv + b2f(Zt[lrow * SK + col]);
        Zt[lrow * SK + col] = __float2bfloat16(v);
      }
  }
  __syncthreads();

  #pragma unroll
  for (int rt = 0; rt < RT; rt++)
    #pragma unroll
    for (int c = 0; c < 2; c++) acc[rt][c] = (floatx4){0.f, 0.f, 0.f, 0.f};
  #pragma unroll
  for (int ks = 0; ks < 4; ks++) {
    short8 bfr0 = *(const short8*)(fuW1 + (((size_t)(wave * 2 + 0) * 4 + ks) * 64 + lane) * 8);
    short8 bfr1 = *(const short8*)(fuW1 + (((size_t)(wave * 2 + 1) * 4 + ks) * 64 + lane) * 8);
    #pragma unroll
    for (int rt = 0; rt < RT; rt++) {
      short8 a = *(const short8*)(&Zt[(rt * 16 + colq) * SK + ks * 32 + quad * 8]);
      acc[rt][0] = __builtin_amdgcn_mfma_f32_16x16x32_bf16(a, bfr0, acc[rt][0], 0, 0, 0);
      acc[rt][1] = __builtin_amdgcn_mfma_f32_16x16x32_bf16(a, bfr1, acc[rt][1], 0, 0, 0);
    }
  }
  #pragma unroll
  for (int c = 0; c < 2; c++) {
    int col = wave * 32 + c * 16 + colq;
    float bv = b2f(fuB1[col]);
    #pragma unroll
    for (int rt = 0; rt < RT; rt++)
      #pragma unroll
      for (int r = 0; r < 4; r++)
        Zt[(rt * 16 + quad * 4 + r) * SK + 128 + col] =
            __float2bfloat16(fmaxf(acc[rt][c][r] + bv, 0.f));
  }
  __syncthreads();

  #pragma unroll
  for (int rt = 0; rt < RT; rt++)
    #pragma unroll
    for (int c = 0; c < 2; c++) acc[rt][c] = (floatx4){0.f, 0.f, 0.f, 0.f};
  #pragma unroll
  for (int ks = 0; ks < 4; ks++) {
    short8 bfr0 = *(const short8*)(fuW2 + (((size_t)(wave * 2 + 0) * 4 + ks) * 64 + lane) * 8);
    short8 bfr1 = *(const short8*)(fuW2 + (((size_t)(wave * 2 + 1) * 4 + ks) * 64 + lane) * 8);
    #pragma unroll
    for (int rt = 0; rt < RT; rt++) {
      short8 a = *(const short8*)(&Zt[(rt * 16 + colq) * SK + 128 + ks * 32 + quad * 8]);
      acc[rt][0] = __builtin_amdgcn_mfma_f32_16x16x32_bf16(a, bfr0, acc[rt][0], 0, 0, 0);
      acc[rt][1] = __builtin_amdgcn_mfma_f32_16x16x32_bf16(a, bfr1, acc[rt][1], 0, 0, 0);
    }
  }
  #pragma unroll
  for (int c = 0; c < 2; c++) {
    int col = wave * 32 + c * 16 + colq;
    float bv = b2f(fuB2[col]);
    #pragma unroll
    for (int rt = 0; rt < RT; rt++)
      #pragma unroll
      for (int r = 0; r < 4; r++) {
        int grow = row0 + rt * 16 + quad * 4 + r;
        if (grow < M) outp[(size_t)grow * HDIM + col] = __float2bfloat16(acc[rt][c][r] + bv);
      }
  }
}

// -------------------------------------------------- typed enc/dec (type-sorted MFMA)
template<int KS1, bool DEC>
__global__ void __launch_bounds__(256) typed_kernel(
    const bf16* __restrict__ in0, const bf16* __restrict__ in1,
    const int* __restrict__ perm, const int* __restrict__ ts, const int* __restrict__ flagp,
    const bf16* __restrict__ W1p, int w1s, const bf16* __restrict__ b1v, int b1s,
    const bf16* __restrict__ W2p, int w2s, const bf16* __restrict__ b2v, int b2s,
    void* __restrict__ outp) {
  constexpr int BM = 64, RT = 4;
  constexpr int SK = KS1 * 32 + 8;
  constexpr int HS = 136;
  int t = blockIdx.y;
  int rs = ts[t], re = ts[t + 1];
  int row0 = rs + blockIdx.x * BM;
  if (row0 >= re) return;
  __shared__ bf16 Zt[BM * SK];
  __shared__ bf16 Hid[BM * HS];
  __shared__ int gIdx[BM];
  const int tid = threadIdx.x;
  const int lane = tid & 63, wave = tid >> 6, colq = lane & 15, quad = lane >> 4;
  for (int i = tid; i < BM; i += 256) gIdx[i] = (row0 + i < re) ? perm[row0 + i] : -1;
  __syncthreads();
  if (DEC) {
    int row = tid >> 2, sub = tid & 3;
    int g = gIdx[row];
    #pragma unroll
    for (int j = 0; j < 4; j++) {
      int seg = j * 4 + sub;
      uint4 v = {0u, 0u, 0u, 0u};
      if (g >= 0) v = *(const uint4*)(in0 + (size_t)g * HDIM + seg * 8);
      *(uint4*)(&Zt[row * SK + seg * 8]) = v;
    }
  } else {
    for (int i = tid; i < BM * 32; i += 256) {
      int row = i >> 5, k = i & 31;
      int g = gIdx[row];
      bf16 v = __float2bfloat16(0.f);
      if (g >= 0 && k < 14) v = (k < 6) ? in0[(size_t)g * 6 + k] : in1[(size_t)g * 8 + (k - 6)];
      Zt[row * SK + k] = v;
    }
  }
  __syncthreads();

  const bf16* W1t = W1p + (size_t)t * w1s;
  const bf16* W2t = W2p + (size_t)t * w2s;
  floatx4 acc[RT][2];
  #pragma unroll
  for (int rt = 0; rt < RT; rt++)
    #pragma unroll
    for (int c = 0; c < 2; c++) acc[rt][c] = (floatx4){0.f, 0.f, 0.f, 0.f};
  #pragma unroll
  for (int ks = 0; ks < KS1; ks++) {
    short8 bfr0 = *(const short8*)(W1t + (((size_t)(wave * 2 + 0) * KS1 + ks) * 64 + lane) * 8);
    short8 bfr1 = *(const short8*)(W1t + (((size_t)(wave * 2 + 1) * KS1 + ks) * 64 + lane) * 8);
    #pragma unroll
    for (int rt = 0; rt < RT; rt++) {
      short8 a = *(const short8*)(&Zt[(rt * 16 + colq) * SK + ks * 32 + quad * 8]);
      acc[rt][0] = __builtin_amdgcn_mfma_f32_16x16x32_bf16(a, bfr0, acc[rt][0], 0, 0, 0);
      acc[rt][1] = __builtin_amdgcn_mfma_f32_16x16x32_bf16(a, bfr1, acc[rt][1], 0, 0, 0);
    }
  }
  #pragma unroll
  for (int c = 0; c < 2; c++) {
    int col = wave * 32 + c * 16 + colq;
    float bv = b2f(b1v[t * b1s + col]);
    #pragma unroll
    for (int rt = 0; rt < RT; rt++)
      #pragma unroll
      for (int r = 0; r < 4; r++) {
        float v = acc[rt][c][r] + bv;
        Hid[(rt * 16 + quad * 4 + r) * HS + col] = __float2bfloat16(fmaxf(v, 0.f));
      }
  }
  __syncthreads();

  floatx4 acc2[RT][2];
  #pragma unroll
  for (int rt = 0; rt < RT; rt++)
    #pragma unroll
    for (int c = 0; c < 2; c++) acc2[rt][c] = (floatx4){0.f, 0.f, 0.f, 0.f};
  #pragma unroll
  for (int ks = 0; ks < 4; ks++) {
    short8 bfr0 = *(const short8*)(W2t + (((size_t)(wave * 2 + 0) * 4 + ks) * 64 + lane) * 8);
    short8 bfr1 = *(const short8*)(W2t + (((size_t)(wave * 2 + 1) * 4 + ks) * 64 + lane) * 8);
    #pragma unroll
    for (int rt = 0; rt < RT; rt++) {
      short8 a = *(const short8*)(&Hid[(rt * 16 + colq) * HS + ks * 32 + quad * 8]);
      acc2[rt][0] = __builtin_amdgcn_mfma_f32_16x16x32_bf16(a, bfr0, acc2[rt][0], 0, 0, 0);
      acc2[rt][1] = __builtin_amdgcn_mfma_f32_16x16x32_bf16(a, bfr1, acc2[rt][1], 0, 0, 0);
    }
  }
  if (DEC) {
    if (wave == 0 && colq < 4) {
      int isBf = flagp[0];
      float bv = b2f(b2v[t * b2s + colq]);
      #pragma unroll
      for (int rt = 0; rt < RT; rt++)
        #pragma unroll
        for (int r = 0; r < 4; r++) {
          int g = gIdx[rt * 16 + quad * 4 + r];
          if (g >= 0) {
            float v = acc2[rt][0][r] + bv;
            if (isBf) ((bf16*)outp)[(size_t)g * 4 + colq] = __float2bfloat16(v);
            else      ((float*)outp)[(size_t)g * 4 + colq] = v;
          }
        }
    }
  } else {
    #pragma unroll
    for (int c = 0; c < 2; c++) {
      int col = wave * 32 + c * 16 + colq;
      float bv = b2f(b2v[t * b2s + col]);
      #pragma unroll
      for (int rt = 0; rt < RT; rt++)
        #pragma unroll
        for (int r = 0; r < 4; r++) {
          int g = gIdx[rt * 16 + quad * 4 + r];
          if (g >= 0) ((bf16*)outp)[(size_t)g * HDIM + col] = __float2bfloat16(acc2[rt][c][r] + bv);
        }
    }
  }
}

// -------------------------------------------------- edge-encoder MLP (attr4 path)
template<int BM>
__global__ void __launch_bounds__(256) ee_kernel(
    const bf16* __restrict__ p0, const int* __restrict__ idx0,
    const bf16* __restrict__ W1p, const bf16* __restrict__ b1v,
    const bf16* __restrict__ W2p, const bf16* __restrict__ b2v,
    bf16* __restrict__ outp, int M) {
  constexpr int RT = BM / 16;
  constexpr int SK = 136;
  __shared__ bf16 Zt[BM * SK];
  const int tid = threadIdx.x;
  const int lane = tid & 63, wave = tid >> 6, colq = lane & 15, quad = lane >> 4;
  const int row0 = blockIdx.x * BM;

  for (int i = tid; i < BM * 4; i += 256) {
    int row = i >> 2, seg = i & 3;
    int gr = row0 + row;
    uint4 val = {0u, 0u, 0u, 0u};
    if (seg == 0 && gr < M) {
      int g = idx0 ? idx0[gr] : gr;
      uint2 v = *(const uint2*)(p0 + (size_t)g * 4);
      val.x = v.x; val.y = v.y;
    }
    *(uint4*)(&Zt[row * SK + seg * 8]) = val;
  }
  __syncthreads();

  floatx4 acc[RT][2];
  #pragma unroll
  for (int rt = 0; rt < RT; rt++)
    #pragma unroll
    for (int c = 0; c < 2; c++) acc[rt][c] = (floatx4){0.f, 0.f, 0.f, 0.f};
  {
    short8 bfr0 = *(const short8*)(W1p + (((size_t)(wave * 2 + 0)) * 64 + lane) * 8);
    short8 bfr1 = *(const short8*)(W1p + (((size_t)(wave * 2 + 1)) * 64 + lane) * 8);
    #pragma unroll
    for (int rt = 0; rt < RT; rt++) {
      short8 a = *(const short8*)(&Zt[(rt * 16 + colq) * SK + quad * 8]);
      acc[rt][0] = __builtin_amdgcn_mfma_f32_16x16x32_bf16(a, bfr0, acc[rt][0], 0, 0, 0);
      acc[rt][1] = __builtin_amdgcn_mfma_f32_16x16x32_bf16(a, bfr1, acc[rt][1], 0, 0, 0);
    }
  }
  __syncthreads();
  #pragma unroll
  for (int c = 0; c < 2; c++) {
    int col = wave * 32 + c * 16 + colq;
    float bv = b2f(b1v[col]);
    #pragma unroll
    for (int rt = 0; rt < RT; rt++)
      #pragma unroll
      for (int r = 0; r < 4; r++)
        Zt[(rt * 16 + quad * 4 + r) * SK + col] =
            __float2bfloat16(fmaxf(acc[rt][c][r] + bv, 0.f));
  }
  __syncthreads();

  floatx4 acc2[RT][2];
  #pragma unroll
  for (int rt = 0; rt < RT; rt++)
    #pragma unroll
    for (int c = 0; c < 2; c++) acc2[rt][c] = (floatx4){0.f, 0.f, 0.f, 0.f};
  #pragma unroll
  for (int ks = 0; ks < 4; ks++) {
    short8 bfr0 = *(const short8*)(W2p + (((size_t)(wave * 2 + 0) * 4 + ks) * 64 + lane) * 8);
    short8 bfr1 = *(const short8*)(W2p + (((size_t)(wave * 2 + 1) * 4 + ks) * 64 + lane) * 8);
    #pragma unroll
    for (int rt = 0; rt < RT; rt++) {
      short8 a = *(const short8*)(&Zt[(rt * 16 + colq) * SK + ks * 32 + quad * 8]);
      acc2[rt][0] = __builtin_amdgcn_mfma_f32_16x16x32_bf16(a, bfr0, acc2[rt][0], 0, 0, 0);
      acc2[rt][1] = __builtin_amdgcn_mfma_f32_16x16x32_bf16(a, bfr1, acc2[rt][1], 0, 0, 0);
    }
  }
  #pragma unroll
  for (int c = 0; c < 2; c++) {
    int col = wave * 32 + c * 16 + colq;
    float bv = b2f(b2v[col]);
    #pragma unroll
    for (int rt = 0; rt < RT; rt++)
      #pragma unroll
      for (int r = 0; r < 4; r++) {
        int grow = row0 + rt * 16 + quad * 4 + r;
        if (grow < M)
          outp[(size_t)grow * HDIM + col] = __float2bfloat16(acc2[rt][c][r] + bv);
      }
  }
}

// ---------------------------------------------------------------- launcher
extern "C" void kernel_launch(void* const* d_in, const int* in_sizes, int n_in,
                              void* d_out, int out_size, void* d_ws, size_t ws_size,
                              hipStream_t stream) {
  const int* edge_index = (const int*)d_in[27];
  const int* node_types = (const int*)d_in[28];
  const int N = in_sizes[28];
  const int E = in_sizes[2] / 4;
  const int L = in_sizes[12] / HDIM;
  const int* srcI = edge_index;
  const int* dstI = edge_index + E;

  CanonDesc cd;
  int total = 0;
  for (int i = 0; i < NCANON; i++) { cd.src[i] = d_in[i]; cd.prefix[i] = total; total += in_sizes[i]; }
  cd.prefix[NCANON] = total;

  char* wsb = (char*)d_ws;
  size_t off = 0;
  auto alloc = [&](size_t bytes) -> void* {
    void* p = wsb + off;
    off += (bytes + 255) & ~(size_t)255;
    return p;
  };
  int*  flag      = (int*)alloc(256);
  bf16* arena     = (bf16*)alloc((size_t)total * 2);
  bf16* h_nodes   = (bf16*)alloc((size_t)N * HDIM * 2);
  bf16* h_edges   = (bf16*)alloc((size_t)E * HDIM * 2);
  float* m_node   = (float*)alloc((size_t)N * HDIM * 4);
  bf16* ysrcb     = (bf16*)alloc((size_t)N * HDIM * 2);
  bf16* ydstb     = (bf16*)alloc((size_t)N * HDIM * 2);
  int* counts     = (int*)alloc((size_t)N * 4);
  int* cursor     = (int*)alloc((size_t)N * 4);
  int* row_start  = (int*)alloc((size_t)(N + 1) * 4);
  int* bsum       = (int*)alloc(260 * 4);
  int* sortedE    = (int*)alloc((size_t)E * 4);
  int* srcS       = (int*)alloc((size_t)E * 4);
  int* dstS       = (int*)alloc((size_t)E * 4);
  int* tsArr      = (int*)alloc(64);
  int* permT      = (int*)alloc((size_t)N * 4);
  bf16* eeW1p  = (bf16*)alloc(4096 * 2);
  bf16* eeW2p  = (bf16*)alloc(16384 * 2);
  bf16* encW1p = (bf16*)alloc(3 * 4096 * 2);
  bf16* encW2p = (bf16*)alloc(3 * 16384 * 2);
  bf16* decW1p = (bf16*)alloc(3 * 16384 * 2);
  bf16* decW2p = (bf16*)alloc(3 * 16384 * 2);
  bf16* euW1a  = (bf16*)alloc((size_t)L * 16384 * 2);
  bf16* euW1b  = (bf16*)alloc((size_t)L * 16384 * 2);
  bf16* euW1c  = (bf16*)alloc((size_t)L * 16384 * 2);
  bf16* euW2p  = (bf16*)alloc((size_t)L * 16384 * 2);
  bf16* nuW1p  = (bf16*)alloc((size_t)L * 32768 * 2);
  bf16* nuW2p  = (bf16*)alloc((size_t)L * 16384 * 2);
  bf16* fuW1p  = (bf16*)alloc((size_t)L * 16384 * 2);
  bf16* fuW2p  = (bf16*)alloc((size_t)L * 16384 * 2);

  const bf16* cX     = arena + cd.prefix[0];
  const bf16* cPE    = arena + cd.prefix[1];
  const bf16* cEA    = arena + cd.prefix[2];
  const bf16* cEncW1 = arena + cd.prefix[3];
  const bf16* cEncB1 = arena + cd.prefix[4];
  const bf16* cEncW2 = arena + cd.prefix[5];
  const bf16* cEncB2 = arena + cd.prefix[6];
  const bf16* cEeW1  = arena + cd.prefix[7];
  const bf16* cEeB1  = arena + cd.prefix[8];
  const bf16* cEeW2  = arena + cd.prefix[9];
  const bf16* cEeB2  = arena + cd.prefix[10];
  const bf16* cEuW1  = arena + cd.prefix[11];
  const bf16* cEuB1  = arena + cd.prefix[12];
  const bf16* cEuW2  = arena + cd.prefix[13];
  const bf16* cEuB2  = arena + cd.prefix[14];
  const bf16* cNuW1  = arena + cd.prefix[15];
  const bf16* cNuB1  = arena + cd.prefix[16];
  const bf16* cNuW2  = arena + cd.prefix[17];
  const bf16* cNuB2  = arena + cd.prefix[18];
  const bf16* cFuW1  = arena + cd.prefix[19];
  const bf16* cFuB1  = arena + cd.prefix[20];
  const bf16* cFuW2  = arena + cd.prefix[21];
  const bf16* cFuB2  = arena + cd.prefix[22];
  const bf16* cDecW1 = arena + cd.prefix[23];
  const bf16* cDecB1 = arena + cd.prefix[24];
  const bf16* cDecW2 = arena + cd.prefix[25];
  const bf16* cDecB2 = arena + cd.prefix[26];

  canon_kernel<<<(total + 255) / 256, 256, 0, stream>>>(
      cd, (const unsigned short*)d_in[0], flag, arena, total);

  hipMemsetAsync(counts, 0, (size_t)N * 4, stream);
  hipMemsetAsync(cursor, 0, (size_t)N * 4, stream);

  PackJobs PJ;
  int nj = 0;
  PJ.j[nj++] = {cEeW1, eeW1p, 4, 1, 128};
  PJ.j[nj++] = {cEeW2, eeW2p, 128, 4, 128};
  for (int l = 0; l < L; l++) {
    const bf16* w1 = cEuW1 + (size_t)l * 384 * HDIM;
    PJ.j[nj++] = {w1,                 euW1a + (size_t)l * 16384, 128, 4, 128};
    PJ.j[nj++] = {w1 + 128 * HDIM,    euW1b + (size_t)l * 16384, 128, 4, 128};
    PJ.j[nj++] = {w1 + 256 * HDIM,    euW1c + (size_t)l * 16384, 128, 4, 128};
    PJ.j[nj++] = {cEuW2 + (size_t)l * HDIM * HDIM, euW2p + (size_t)l * 16384, 128, 4, 128};
    PJ.j[nj++] = {cNuW1 + (size_t)l * 256 * HDIM,  nuW1p + (size_t)l * 32768, 256, 8, 128};
    PJ.j[nj++] = {cNuW2 + (size_t)l * HDIM * HDIM, nuW2p + (size_t)l * 16384, 128, 4, 128};
    PJ.j[nj++] = {cFuW1 + (size_t)l * HDIM * HDIM, fuW1p + (size_t)l * 16384, 128, 4, 128};
    PJ.j[nj++] = {cFuW2 + (size_t)l * HDIM * HDIM, fuW2p + (size_t)l * 16384, 128, 4, 128};
  }
  for (int t = 0; t < 3; t++) {
    PJ.j[nj++] = {cEncW1 + (size_t)t * 14 * HDIM,   encW1p + (size_t)t * 4096, 14, 1, 128};
    PJ.j[nj++] = {cEncW2 + (size_t)t * HDIM * HDIM, encW2p + (size_t)t * 16384, 128, 4, 128};
    PJ.j[nj++] = {cDecW1 + (size_t)t * HDIM * HDIM, decW1p + (size_t)t * 16384, 128, 4, 128};
    PJ.j[nj++] = {cDecW2 + (size_t)t * HDIM * 4,    decW2p + (size_t)t * 16384, 128, 4, 4};
  }
  pack_all_kernel<<<dim3(16, nj), 256, 0, stream>>>(PJ);

  // CSR (dst-sorted edges)
  int nb = (N + 255) / 256;
  hist_kernel<<<(E + 255) / 256, 256, 0, stream>>>(dstI, counts, E);
  scan1_kernel<<<nb, 256, 0, stream>>>(counts, bsum, N);
  scan2_kernel<<<1, 64, 0, stream>>>(bsum, nb);
  scan3_kernel<<<nb, 256, 0, stream>>>(counts, bsum, row_start, N, nb);
  scatter_kernel<<<(E + 255) / 256, 256, 0, stream>>>(srcI, dstI, row_start, cursor,
                                                      sortedE, srcS, dstS, E);
  tsort_kernel<<<1, 1024, 0, stream>>>(node_types, tsArr, permT, N);

  int ngrid64 = (N + 63) / 64;
  typed_kernel<1, false><<<dim3(ngrid64, 3), 256, 0, stream>>>(
      cX, cPE, permT, tsArr, flag, encW1p, 4096, cEncB1, HDIM,
      encW2p, 16384, cEncB2, HDIM, h_nodes);

  int egrid32  = (E + 31) / 32;
  int egrid128 = (E + 127) / 128;

  ee_kernel<128><<<egrid128, 256, 0, stream>>>(
      cEA, sortedE, eeW1p, cEeB1, eeW2p, cEeB2, h_edges, E);

  for (int l = 0; l < L; l++) {
    ygemm_kernel<<<dim3(ngrid64, 2), 256, 0, stream>>>(
        h_nodes, euW1a + (size_t)l * 16384, euW1b + (size_t)l * 16384, ysrcb, ydstb, m_node, N);
    if (l + 1 < L) {
      eu_kernel<32, true><<<egrid32, 256, 0, stream>>>(
          h_edges, ysrcb, ydstb, srcS, dstS,
          euW1c + (size_t)l * 16384, cEuB1 + l * HDIM,
          euW2p + (size_t)l * 16384, cEuB2 + l * HDIM, h_edges, m_node, E);
    } else {
      eu_kernel<32, false><<<egrid32, 256, 0, stream>>>(   // last layer: h_edges dead after agg
          h_edges, ysrcb, ydstb, srcS, dstS,
          euW1c + (size_t)l * 16384, cEuB1 + l * HDIM,
          euW2p + (size_t)l * 16384, cEuB2 + l * HDIM, h_edges, m_node, E);
    }
    node_kernel<<<ngrid64, 256, 0, stream>>>(
        h_nodes, m_node,
        nuW1p + (size_t)l * 32768, cNuB1 + l * HDIM,
        nuW2p + (size_t)l * 16384, cNuB2 + l * HDIM,
        fuW1p + (size_t)l * 16384, cFuB1 + l * HDIM,
        fuW2p + (size_t)l * 16384, cFuB2 + l * HDIM, h_nodes, N);
  }

  typed_kernel<4, true><<<dim3(ngrid64, 3), 256, 0, stream>>>(
      h_nodes, nullptr, permT, tsArr, flag, decW1p, 16384, cDecB1, HDIM,
      decW2p, 16384, cDecB2, 4, d_out);
  (void)n_in; (void)ws_size;
}

// Round 11
// 476.224 us; speedup vs baseline: 1.2435x; 1.0428x over previous
//
#include <hip/hip_runtime.h>
#include <hip/hip_bf16.h>

typedef __hip_bfloat16 bf16;
typedef __attribute__((ext_vector_type(8))) short short8;   // 8 bf16 frag
typedef __attribute__((ext_vector_type(4))) float floatx4;  // MFMA C/D frag

#define HDIM 128
#define NCANON 27

__device__ __forceinline__ float b2f(bf16 v) { return __bfloat162float(v); }
__device__ __forceinline__ float s2f(short s) {
  return __uint_as_float(((unsigned int)(unsigned short)s) << 16);
}
__device__ __forceinline__ short f2s(float f) {
  return (short)__bfloat16_as_ushort(__float2bfloat16(f));
}

struct CanonDesc {
  const void* src[NCANON];
  int prefix[NCANON + 1];
};

// ---- canon with inlined dtype detect (block 0 publishes flag for the decoder)
__global__ void canon_kernel(CanonDesc d, const unsigned short* __restrict__ xraw,
                             int* __restrict__ flagOut, bf16* __restrict__ out, int total) {
  __shared__ int sflag;
  int tid = threadIdx.x;
  if (tid < 64) {
    unsigned short u = xraw[2 * tid];
    int e = (u >> 7) & 0xFF;
    int ok = (u == 0) || (e >= 100 && e <= 140);
    unsigned long long m = __ballot(ok);
    if (tid == 0) sflag = (__popcll(m) >= 48) ? 1 : 0;
  }
  __syncthreads();
  int isBf = sflag;
  if (blockIdx.x == 0 && tid == 0) flagOut[0] = isBf;
  int t = blockIdx.x * 256 + tid;
  if (t >= total) return;
  int lo = 0, hi = NCANON;
  while (lo + 1 < hi) { int mid = (lo + hi) >> 1; if (d.prefix[mid] <= t) lo = mid; else hi = mid; }
  int off = t - d.prefix[lo];
  out[t] = isBf ? ((const bf16*)d.src[lo])[off]
                : __float2bfloat16(((const float*)d.src[lo])[off]);
}

// ---------------------------------------------------------------- CSR build
__global__ void hist_kernel(const int* __restrict__ dst, int* __restrict__ cnt, int E) {
  int e = blockIdx.x * 256 + threadIdx.x;
  if (e < E) atomicAdd(&cnt[dst[e]], 1);
}

__global__ void scan1_kernel(const int* __restrict__ cnt, int* __restrict__ bsum, int n) {
  int tid = threadIdx.x, lane = tid & 63, wave = tid >> 6;
  int i = blockIdx.x * 256 + tid;
  int v = (i < n) ? cnt[i] : 0;
  #pragma unroll
  for (int d = 32; d; d >>= 1) v += __shfl_down(v, d);
  __shared__ int ws[4];
  if (lane == 0) ws[wave] = v;
  __syncthreads();
  if (tid == 0) bsum[blockIdx.x] = ws[0] + ws[1] + ws[2] + ws[3];
}

__global__ void scan2_kernel(int* __restrict__ bsum, int nb) {   // nb <= 128; 64 threads
  int lane = threadIdx.x;
  int a0 = (lane < nb) ? bsum[lane] : 0;
  int b0 = (64 + lane < nb) ? bsum[64 + lane] : 0;
  int a = a0, b = b0;
  #pragma unroll
  for (int d = 1; d < 64; d <<= 1) { int t = __shfl_up(a, d); if (lane >= d) a += t; }
  int totA = __shfl(a, 63);
  #pragma unroll
  for (int d = 1; d < 64; d <<= 1) { int t = __shfl_up(b, d); if (lane >= d) b += t; }
  int totB = __shfl(b, 63);
  if (lane < nb) bsum[lane] = a - a0;
  if (64 + lane < nb) bsum[64 + lane] = b - b0 + totA;
  if (lane == 0) bsum[nb] = totA + totB;
}

__global__ void scan3_kernel(const int* __restrict__ cnt, const int* __restrict__ bsum,
                             int* __restrict__ row_start, int n, int nb) {
  __shared__ int sh[256];
  int tid = threadIdx.x;
  int i = blockIdx.x * 256 + tid;
  int v = (i < n) ? cnt[i] : 0;
  sh[tid] = v;
  __syncthreads();
  #pragma unroll
  for (int off = 1; off < 256; off <<= 1) {
    int t = (tid >= off) ? sh[tid - off] : 0;
    __syncthreads();
    sh[tid] += t;
    __syncthreads();
  }
  if (i < n) row_start[i] = bsum[blockIdx.x] + sh[tid] - v;
  if (blockIdx.x == 0 && tid == 0) row_start[n] = bsum[nb];
}

// scatter: also permutes edge_attr into dst-sorted order (removes ee's gather)
__global__ void scatter_kernel(const int* __restrict__ src, const int* __restrict__ dst,
                               const int* __restrict__ row_start, int* __restrict__ cursor,
                               const bf16* __restrict__ ea, bf16* __restrict__ eaS,
                               int* __restrict__ srcS, int* __restrict__ dstS, int E) {
  int e = blockIdx.x * 256 + threadIdx.x;
  if (e < E) {
    int d = dst[e];
    int pos = row_start[d] + atomicAdd(&cursor[d], 1);
    srcS[pos] = src[e];
    dstS[pos] = d;
    *(uint2*)(eaS + (size_t)pos * 4) = *(const uint2*)(ea + (size_t)e * 4);
  }
}

// --------- type permutation: single-block atomic-free stable counting sort
__global__ void __launch_bounds__(1024) tsort_kernel(const int* __restrict__ types,
                                                     int* __restrict__ ts,
                                                     int* __restrict__ perm, int n) {
  __shared__ int wc[16][3];
  __shared__ int base[3];
  int tid = threadIdx.x, lane = tid & 63, wave = tid >> 6;
  int c0 = 0, c1 = 0, c2 = 0;
  for (int i = tid; i < n; i += 1024) {
    int t = types[i];
    c0 += (t == 0); c1 += (t == 1); c2 += (t == 2);
  }
  #pragma unroll
  for (int d = 32; d; d >>= 1) {
    c0 += __shfl_down(c0, d); c1 += __shfl_down(c1, d); c2 += __shfl_down(c2, d);
  }
  if (lane == 0) { wc[wave][0] = c0; wc[wave][1] = c1; wc[wave][2] = c2; }
  __syncthreads();
  if (tid == 0) {
    int t0 = 0, t1 = 0;
    for (int w = 0; w < 16; w++) { t0 += wc[w][0]; t1 += wc[w][1]; }
    ts[0] = 0; ts[1] = t0; ts[2] = t0 + t1; ts[3] = n;
    base[0] = 0; base[1] = t0; base[2] = t0 + t1;
  }
  __syncthreads();
  for (int i0 = 0; i0 < n; i0 += 1024) {
    int i = i0 + tid;
    int t = (i < n) ? types[i] : -1;
    unsigned long long m0 = __ballot(t == 0);
    unsigned long long m1 = __ballot(t == 1);
    unsigned long long m2 = __ballot(t == 2);
    if (lane == 0) { wc[wave][0] = __popcll(m0); wc[wave][1] = __popcll(m1); wc[wave][2] = __popcll(m2); }
    __syncthreads();
    if (i < n) {
      unsigned long long mt = (t == 0) ? m0 : ((t == 1) ? m1 : m2);
      unsigned long long below = (lane == 0) ? 0ull : ((1ull << lane) - 1ull);
      int r = __popcll(mt & below);
      int woff = 0;
      for (int w = 0; w < wave; w++) woff += wc[w][t];
      perm[base[t] + woff + r] = i;
    }
    __syncthreads();
    if (tid == 0) {
      int a0 = 0, a1 = 0, a2 = 0;
      for (int w = 0; w < 16; w++) { a0 += wc[w][0]; a1 += wc[w][1]; a2 += wc[w][2]; }
      base[0] += a0; base[1] += a1; base[2] += a2;
    }
    __syncthreads();
  }
}

// -------------------------------------------------- fused weight pre-pack (B-frag order)
struct PackJob { const bf16* src; bf16* dst; int Ksrc; int KS; int srcCols; };
struct PackJobs { PackJob j[40]; };

__global__ void pack_all_kernel(PackJobs J) {
  PackJob job = J.j[blockIdx.y];
  int idx = blockIdx.x * 256 + threadIdx.x;
  int total = 8 * job.KS * 64;
  if (idx >= total) return;
  int lane = idx & 63;
  int ks = (idx >> 6) % job.KS;
  int ct = idx / (64 * job.KS);
  bf16* o = job.dst + (size_t)idx * 8;
  int ncol = ct * 16 + (lane & 15);
  int kb = ks * 32 + ((lane >> 4) & 3) * 8;
  #pragma unroll
  for (int jj = 0; jj < 8; jj++) {
    int k = kb + jj;
    o[jj] = (k < job.Ksrc && ncol < job.srcCols)
              ? job.src[(size_t)k * job.srcCols + ncol] : __float2bfloat16(0.f);
  }
}

// ------------- per-node Y = h @ W1a / W1b (bf16 out) + zero m_node (layer 0 only)
__global__ void __launch_bounds__(256) ygemm_kernel(
    const bf16* __restrict__ X,
    const bf16* __restrict__ WpA, const bf16* __restrict__ WpB,
    bf16* __restrict__ outA, bf16* __restrict__ outB,
    float* __restrict__ mnode, int M) {
  const bf16* Wp = blockIdx.y ? WpB : WpA;
  bf16* outp = blockIdx.y ? outB : outA;
  constexpr int BM = 64, RT = 4, SK = 136;
  __shared__ bf16 Zt[BM * SK];
  const int tid = threadIdx.x;
  const int lane = tid & 63, wave = tid >> 6, colq = lane & 15, quad = lane >> 4;
  const int row0 = blockIdx.x * BM;
  if (blockIdx.y == 0) {
    float4 z = {0.f, 0.f, 0.f, 0.f};
    for (int i = tid; i < BM * 32; i += 256) {
      int row = i >> 5, q = i & 31;
      int gr = row0 + row;
      if (gr < M) *(float4*)(mnode + (size_t)gr * HDIM + q * 4) = z;
    }
  }
  {
    int row = tid >> 2, sub = tid & 3;
    int gr = row0 + row;
    bool ok = gr < M;
    #pragma unroll
    for (int j = 0; j < 4; j++) {
      int seg = j * 4 + sub;
      uint4 v = {0u, 0u, 0u, 0u};
      if (ok) v = *(const uint4*)(X + (size_t)gr * HDIM + seg * 8);
      *(uint4*)(&Zt[row * SK + seg * 8]) = v;
    }
  }
  __syncthreads();
  floatx4 acc[RT][2];
  #pragma unroll
  for (int rt = 0; rt < RT; rt++)
    #pragma unroll
    for (int c = 0; c < 2; c++) acc[rt][c] = (floatx4){0.f, 0.f, 0.f, 0.f};
  #pragma unroll
  for (int ks = 0; ks < 4; ks++) {
    short8 bfr0 = *(const short8*)(Wp + (((size_t)(wave * 2 + 0) * 4 + ks) * 64 + lane) * 8);
    short8 bfr1 = *(const short8*)(Wp + (((size_t)(wave * 2 + 1) * 4 + ks) * 64 + lane) * 8);
    #pragma unroll
    for (int rt = 0; rt < RT; rt++) {
      short8 a = *(const short8*)(&Zt[(rt * 16 + colq) * SK + ks * 32 + quad * 8]);
      acc[rt][0] = __builtin_amdgcn_mfma_f32_16x16x32_bf16(a, bfr0, acc[rt][0], 0, 0, 0);
      acc[rt][1] = __builtin_amdgcn_mfma_f32_16x16x32_bf16(a, bfr1, acc[rt][1], 0, 0, 0);
    }
  }
  #pragma unroll
  for (int c = 0; c < 2; c++) {
    int col = wave * 32 + c * 16 + colq;
    #pragma unroll
    for (int rt = 0; rt < RT; rt++)
      #pragma unroll
      for (int r = 0; r < 4; r++) {
        int grow = row0 + rt * 16 + quad * 4 + r;
        if (grow < M) outp[(size_t)grow * HDIM + col] = __float2bfloat16(acc[rt][c][r]);
      }
  }
}

// ----------------------- edge-update + fused dst-segment aggregation
template<int BM, bool WRITE_HE>
__global__ void __launch_bounds__(256) eu_kernel(
    const bf16* __restrict__ he, const bf16* __restrict__ ysrc, const bf16* __restrict__ ydst,
    const int* __restrict__ srcS, const int* __restrict__ dstS,
    const bf16* __restrict__ W1p, const bf16* __restrict__ b1v,
    const bf16* __restrict__ W2p, const bf16* __restrict__ b2v,
    bf16* __restrict__ outp, float* __restrict__ mnode, int M) {
  constexpr int RT = BM / 16;
  constexpr int SK = 264;
  __shared__ bf16 Zt[BM * SK];
  __shared__ int dstLds[BM];
  const int tid = threadIdx.x;
  const int lane = tid & 63, wave = tid >> 6, colq = lane & 15, quad = lane >> 4;
  const int row0 = blockIdx.x * BM;
  constexpr int TPR = 256 / BM;
  {
    int row = tid / TPR, sub = tid % TPR;
    int gr = row0 + row;
    bool ok = gr < M;
    int g0 = ok ? srcS[gr] : 0;
    int g1 = ok ? dstS[gr] : 0;
    if (sub == 0) dstLds[row] = ok ? g1 : -1;
    #pragma unroll
    for (int j = 0; j < 32 / TPR; j++) {
      int c = j * TPR + sub;
      int part = c >> 4, seg = c & 15;
      if (part == 0) {
        short8 o = {0, 0, 0, 0, 0, 0, 0, 0};
        if (ok) {
          short8 a = *(const short8*)(ysrc + (size_t)g0 * HDIM + seg * 8);
          short8 b = *(const short8*)(ydst + (size_t)g1 * HDIM + seg * 8);
          #pragma unroll
          for (int k = 0; k < 8; k++) o[k] = f2s(s2f(a[k]) + s2f(b[k]));
        }
        *(short8*)(&Zt[row * SK + seg * 8]) = o;
      } else {
        uint4 v = {0u, 0u, 0u, 0u};
        if (ok) v = *(const uint4*)(he + (size_t)gr * HDIM + seg * 8);
        *(uint4*)(&Zt[row * SK + 128 + seg * 8]) = v;
      }
    }
  }
  __syncthreads();

  floatx4 acc[RT][2];
  #pragma unroll
  for (int rt = 0; rt < RT; rt++)
    #pragma unroll
    for (int c = 0; c < 2; c++) acc[rt][c] = (floatx4){0.f, 0.f, 0.f, 0.f};
  #pragma unroll
  for (int ks = 0; ks < 4; ks++) {
    short8 bfr0 = *(const short8*)(W1p + (((size_t)(wave * 2 + 0) * 4 + ks) * 64 + lane) * 8);
    short8 bfr1 = *(const short8*)(W1p + (((size_t)(wave * 2 + 1) * 4 + ks) * 64 + lane) * 8);
    #pragma unroll
    for (int rt = 0; rt < RT; rt++) {
      short8 a = *(const short8*)(&Zt[(rt * 16 + colq) * SK + 128 + ks * 32 + quad * 8]);
      acc[rt][0] = __builtin_amdgcn_mfma_f32_16x16x32_bf16(a, bfr0, acc[rt][0], 0, 0, 0);
      acc[rt][1] = __builtin_amdgcn_mfma_f32_16x16x32_bf16(a, bfr1, acc[rt][1], 0, 0, 0);
    }
  }
  #pragma unroll
  for (int c = 0; c < 2; c++) {
    int col = wave * 32 + c * 16 + colq;
    float bv = b2f(b1v[col]);
    #pragma unroll
    for (int rt = 0; rt < RT; rt++)
      #pragma unroll
      for (int r = 0; r < 4; r++) {
        int lrow = rt * 16 + quad * 4 + r;
        float v = acc[rt][c][r] + bv + b2f(Zt[lrow * SK + col]);
        Zt[lrow * SK + col] = __float2bfloat16(fmaxf(v, 0.f));
      }
  }
  __syncthreads();

  floatx4 acc2[RT][2];
  #pragma unroll
  for (int rt = 0; rt < RT; rt++)
    #pragma unroll
    for (int c = 0; c < 2; c++) acc2[rt][c] = (floatx4){0.f, 0.f, 0.f, 0.f};
  #pragma unroll
  for (int ks = 0; ks < 4; ks++) {
    short8 bfr0 = *(const short8*)(W2p + (((size_t)(wave * 2 + 0) * 4 + ks) * 64 + lane) * 8);
    short8 bfr1 = *(const short8*)(W2p + (((size_t)(wave * 2 + 1) * 4 + ks) * 64 + lane) * 8);
    #pragma unroll
    for (int rt = 0; rt < RT; rt++) {
      short8 a = *(const short8*)(&Zt[(rt * 16 + colq) * SK + ks * 32 + quad * 8]);
      acc2[rt][0] = __builtin_amdgcn_mfma_f32_16x16x32_bf16(a, bfr0, acc2[rt][0], 0, 0, 0);
      acc2[rt][1] = __builtin_amdgcn_mfma_f32_16x16x32_bf16(a, bfr1, acc2[rt][1], 0, 0, 0);
    }
  }
  #pragma unroll
  for (int c = 0; c < 2; c++) {
    int col = wave * 32 + c * 16 + colq;
    float bv = b2f(b2v[col]);
    #pragma unroll
    for (int rt = 0; rt < RT; rt++)
      #pragma unroll
      for (int r = 0; r < 4; r++) {
        int lrow = rt * 16 + quad * 4 + r;
        int grow = row0 + lrow;
        float v = acc2[rt][c][r] + bv + b2f(Zt[lrow * SK + 128 + col]);
        bf16 vb = __float2bfloat16(v);
        Zt[lrow * SK + 128 + col] = vb;
        if (WRITE_HE && grow < M) outp[(size_t)grow * HDIM + col] = vb;
      }
  }
  __syncthreads();

  {
    int col = tid & 127;
    int half = tid >> 7;
    int rbeg = half * (BM / 2), rend = rbeg + (BM / 2);
    float s = 0.f;
    int runDst = dstLds[rbeg];
    bool touchStart = true;
    for (int r = rbeg; r < rend; r++) {
      int d = dstLds[r];
      if (d != runDst) {
        if (runDst >= 0) {
          float* mp = &mnode[(size_t)runDst * HDIM + col];
          if (touchStart) atomicAdd(mp, s); else *mp = s;
        }
        runDst = d; s = 0.f; touchStart = false;
      }
      s += b2f(Zt[r * SK + 128 + col]);
    }
    if (runDst >= 0) atomicAdd(&mnode[(size_t)runDst * HDIM + col], s);
  }
}

// ----------------------- fused node update + fusion MLP (+ next-layer Y emit)
// local = h + ReLU([h||m]W1n+b1n)W2n+b2n ; h' = ReLU(local W1f+b1f)W2f+b2f
// If yW1a: Y_src = h'@yW1a, Y_dst = h'@yW1b (for next layer's eu); m_node
// rows zeroed in-place right after staging (ready for next eu's atomics).
__global__ void __launch_bounds__(256) node_kernel(
    const bf16* __restrict__ h_nodes, float* __restrict__ mnode,
    const bf16* __restrict__ nuW1, const bf16* __restrict__ nuB1,
    const bf16* __restrict__ nuW2, const bf16* __restrict__ nuB2,
    const bf16* __restrict__ fuW1, const bf16* __restrict__ fuB1,
    const bf16* __restrict__ fuW2, const bf16* __restrict__ fuB2,
    const bf16* __restrict__ yW1a, const bf16* __restrict__ yW1b,
    bf16* __restrict__ ysA, bf16* __restrict__ ysB,
    bf16* __restrict__ outp, int M) {
  constexpr int BM = 64, RT = 4, SK = 264;
  __shared__ bf16 Zt[BM * SK];
  const int tid = threadIdx.x;
  const int lane = tid & 63, wave = tid >> 6, colq = lane & 15, quad = lane >> 4;
  const int row0 = blockIdx.x * BM;
  {
    int row = tid >> 2, sub = tid & 3;
    int gr = row0 + row;
    bool ok = gr < M;
    float4 z4 = {0.f, 0.f, 0.f, 0.f};
    #pragma unroll
    for (int j = 0; j < 8; j++) {
      int c = j * 4 + sub;
      int part = c >> 4, seg = c & 15;
      if (part == 0) {
        uint4 v = {0u, 0u, 0u, 0u};
        if (ok) v = *(const uint4*)(h_nodes + (size_t)gr * HDIM + seg * 8);
        *(uint4*)(&Zt[row * SK + seg * 8]) = v;
      } else {
        short8 o = {0, 0, 0, 0, 0, 0, 0, 0};
        if (ok) {
          float* mp = mnode + (size_t)gr * HDIM + seg * 8;
          #pragma unroll
          for (int k = 0; k < 8; k++) o[k] = f2s(mp[k]);
          if (yW1a) { *(float4*)(mp) = z4; *(float4*)(mp + 4) = z4; }  // zero for next layer
        }
        *(short8*)(&Zt[row * SK + 128 + seg * 8]) = o;
      }
    }
  }
  __syncthreads();

  floatx4 acc[RT][2];
  #pragma unroll
  for (int rt = 0; rt < RT; rt++)
    #pragma unroll
    for (int c = 0; c < 2; c++) acc[rt][c] = (floatx4){0.f, 0.f, 0.f, 0.f};
  #pragma unroll
  for (int ks = 0; ks < 8; ks++) {
    short8 bfr0 = *(const short8*)(nuW1 + (((size_t)(wave * 2 + 0) * 8 + ks) * 64 + lane) * 8);
    short8 bfr1 = *(const short8*)(nuW1 + (((size_t)(wave * 2 + 1) * 8 + ks) * 64 + lane) * 8);
    #pragma unroll
    for (int rt = 0; rt < RT; rt++) {
      short8 a = *(const short8*)(&Zt[(rt * 16 + colq) * SK + ks * 32 + quad * 8]);
      acc[rt][0] = __builtin_amdgcn_mfma_f32_16x16x32_bf16(a, bfr0, acc[rt][0], 0, 0, 0);
      acc[rt][1] = __builtin_amdgcn_mfma_f32_16x16x32_bf16(a, bfr1, acc[rt][1], 0, 0, 0);
    }
  }
  __syncthreads();
  #pragma unroll
  for (int c = 0; c < 2; c++) {
    int col = wave * 32 + c * 16 + colq;
    float bv = b2f(nuB1[col]);
    #pragma unroll
    for (int rt = 0; rt < RT; rt++)
      #pragma unroll
      for (int r = 0; r < 4; r++)
        Zt[(rt * 16 + quad * 4 + r) * SK + 128 + col] =
            __float2bfloat16(fmaxf(acc[rt][c][r] + bv, 0.f));
  }
  __syncthreads();

  #pragma unroll
  for (int rt = 0; rt < RT; rt++)
    #pragma unroll
    for (int c = 0; c < 2; c++) acc[rt][c] = (floatx4){0.f, 0.f, 0.f, 0.f};
  #pragma unroll
  for (int ks = 0; ks < 4; ks++) {
    short8 bfr0 = *(const short8*)(nuW2 + (((size_t)(wave * 2 + 0) * 4 + ks) * 64 + lane) * 8);
    short8 bfr1 = *(const short8*)(nuW2 + (((size_t)(wave * 2 + 1) * 4 + ks) * 64 + lane) * 8);
    #pragma unroll
    for (int rt = 0; rt < RT; rt++) {
      short8 a = *(const short8*)(&Zt[(rt * 16 + colq) * SK + 128 + ks * 32 + quad * 8]);
      acc[rt][0] = __builtin_amdgcn_mfma_f32_16x16x32_bf16(a, bfr0, acc[rt][0], 0, 0, 0);
      acc[rt][1] = __builtin_amdgcn_mfma_f32_16x16x32_bf16(a, bfr1, acc[rt][1], 0, 0, 0);
    }
  }
  #pragma unroll
  for (int c = 0; c < 2; c++) {
    int col = wave * 32 + c * 16 + colq;
    float bv = b2f(nuB2[col]);
    #pragma unroll
    for (int rt = 0; rt < RT; rt++)
      #pragma unroll
      for (int r = 0; r < 4; r++) {
        int lrow = rt * 16 + quad * 4 + r;
        float v = acc[rt][c][r] + bv + b2f(Zt[lrow * SK + col]);
        Zt[lrow * SK + col] = __float2bfloat16(v);
      }
  }
  __syncthreads();

  #pragma unroll
  for (int rt = 0; rt < RT; rt++)
    #pragma unroll
    for (int c = 0; c < 2; c++) acc[rt][c] = (floatx4){0.f, 0.f, 0.f, 0.f};
  #pragma unroll
  for (int ks = 0; ks < 4; ks++) {
    short8 bfr0 = *(const short8*)(fuW1 + (((size_t)(wave * 2 + 0) * 4 + ks) * 64 + lane) * 8);
    short8 bfr1 = *(const short8*)(fuW1 + (((size_t)(wave * 2 + 1) * 4 + ks) * 64 + lane) * 8);
    #pragma unroll
    for (int rt = 0; rt < RT; rt++) {
      short8 a = *(const short8*)(&Zt[(rt * 16 + colq) * SK + ks * 32 + quad * 8]);
      acc[rt][0] = __builtin_amdgcn_mfma_f32_16x16x32_bf16(a, bfr0, acc[rt][0], 0, 0, 0);
      acc[rt][1] = __builtin_amdgcn_mfma_f32_16x16x32_bf16(a, bfr1, acc[rt][1], 0, 0, 0);
    }
  }
  #pragma unroll
  for (int c = 0; c < 2; c++) {
    int col = wave * 32 + c * 16 + colq;
    float bv = b2f(fuB1[col]);
    #pragma unroll
    for (int rt = 0; rt < RT; rt++)
      #pragma unroll
      for (int r = 0; r < 4; r++)
        Zt[(rt * 16 + quad * 4 + r) * SK + 128 + col] =
            __float2bfloat16(fmaxf(acc[rt][c][r] + bv, 0.f));
  }
  __syncthreads();

  #pragma unroll
  for (int rt = 0; rt < RT; rt++)
    #pragma unroll
    for (int c = 0; c < 2; c++) acc[rt][c] = (floatx4){0.f, 0.f, 0.f, 0.f};
  #pragma unroll
  for (int ks = 0; ks < 4; ks++) {
    short8 bfr0 = *(const short8*)(fuW2 + (((size_t)(wave * 2 + 0) * 4 + ks) * 64 + lane) * 8);
    short8 bfr1 = *(const short8*)(fuW2 + (((size_t)(wave * 2 + 1) * 4 + ks) * 64 + lane) * 8);
    #pragma unroll
    for (int rt = 0; rt < RT; rt++) {
      short8 a = *(const short8*)(&Zt[(rt * 16 + colq) * SK + 128 + ks * 32 + quad * 8]);
      acc[rt][0] = __builtin_amdgcn_mfma_f32_16x16x32_bf16(a, bfr0, acc[rt][0], 0, 0, 0);
      acc[rt][1] = __builtin_amdgcn_mfma_f32_16x16x32_bf16(a, bfr1, acc[rt][1], 0, 0, 0);
    }
  }
  // h' -> global + LDS part0 (dead after fu-GEMM1; all waves past that barrier)
  #pragma unroll
  for (int c = 0; c < 2; c++) {
    int col = wave * 32 + c * 16 + colq;
    float bv = b2f(fuB2[col]);
    #pragma unroll
    for (int rt = 0; rt < RT; rt++)
      #pragma unroll
      for (int r = 0; r < 4; r++) {
        int lrow = rt * 16 + quad * 4 + r;
        int grow = row0 + lrow;
        bf16 hb = __float2bfloat16(acc[rt][c][r] + bv);
        Zt[lrow * SK + col] = hb;
        if (grow < M) outp[(size_t)grow * HDIM + col] = hb;
      }
  }
  if (!yW1a) return;
  __syncthreads();

  // ---- next-layer Y GEMMs: Y = h' @ yW1{a,b}
  #pragma unroll
  for (int which = 0; which < 2; which++) {
    const bf16* Wp = which ? yW1b : yW1a;
    bf16* outy = which ? ysB : ysA;
    #pragma unroll
    for (int rt = 0; rt < RT; rt++)
      #pragma unroll
      for (int c = 0; c < 2; c++) acc[rt][c] = (floatx4){0.f, 0.f, 0.f, 0.f};
    #pragma unroll
    for (int ks = 0; ks < 4; ks++) {
      short8 bfr0 = *(const short8*)(Wp + (((size_t)(wave * 2 + 0) * 4 + ks) * 64 + lane) * 8);
      short8 bfr1 = *(const short8*)(Wp + (((size_t)(wave * 2 + 1) * 4 + ks) * 64 + lane) * 8);
      #pragma unroll
      for (int rt = 0; rt < RT; rt++) {
        short8 a = *(const short8*)(&Zt[(rt * 16 + colq) * SK + ks * 32 + quad * 8]);
        acc[rt][0] = __builtin_amdgcn_mfma_f32_16x16x32_bf16(a, bfr0, acc[rt][0], 0, 0, 0);
        acc[rt][1] = __builtin_amdgcn_mfma_f32_16x16x32_bf16(a, bfr1, acc[rt][1], 0, 0, 0);
      }
    }
    #pragma unroll
    for (int c = 0; c < 2; c++) {
      int col = wave * 32 + c * 16 + colq;
      #pragma unroll
      for (int rt = 0; rt < RT; rt++)
        #pragma unroll
        for (int r = 0; r < 4; r++) {
          int grow = row0 + rt * 16 + quad * 4 + r;
          if (grow < M) outy[(size_t)grow * HDIM + col] = __float2bfloat16(acc[rt][c][r]);
        }
    }
  }
}

// -------------------------------------------------- typed enc/dec (type-sorted MFMA)
template<int KS1, bool DEC>
__global__ void __launch_bounds__(256) typed_kernel(
    const bf16* __restrict__ in0, const bf16* __restrict__ in1,
    const int* __restrict__ perm, const int* __restrict__ ts, const int* __restrict__ flagp,
    const bf16* __restrict__ W1p, int w1s, const bf16* __restrict__ b1v, int b1s,
    const bf16* __restrict__ W2p, int w2s, const bf16* __restrict__ b2v, int b2s,
    void* __restrict__ outp) {
  constexpr int BM = 64, RT = 4;
  constexpr int SK = KS1 * 32 + 8;
  constexpr int HS = 136;
  int t = blockIdx.y;
  int rs = ts[t], re = ts[t + 1];
  int row0 = rs + blockIdx.x * BM;
  if (row0 >= re) return;
  __shared__ bf16 Zt[BM * SK];
  __shared__ bf16 Hid[BM * HS];
  __shared__ int gIdx[BM];
  const int tid = threadIdx.x;
  const int lane = tid & 63, wave = tid >> 6, colq = lane & 15, quad = lane >> 4;
  for (int i = tid; i < BM; i += 256) gIdx[i] = (row0 + i < re) ? perm[row0 + i] : -1;
  __syncthreads();
  if (DEC) {
    int row = tid >> 2, sub = tid & 3;
    int g = gIdx[row];
    #pragma unroll
    for (int j = 0; j < 4; j++) {
      int seg = j * 4 + sub;
      uint4 v = {0u, 0u, 0u, 0u};
      if (g >= 0) v = *(const uint4*)(in0 + (size_t)g * HDIM + seg * 8);
      *(uint4*)(&Zt[row * SK + seg * 8]) = v;
    }
  } else {
    for (int i = tid; i < BM * 32; i += 256) {
      int row = i >> 5, k = i & 31;
      int g = gIdx[row];
      bf16 v = __float2bfloat16(0.f);
      if (g >= 0 && k < 14) v = (k < 6) ? in0[(size_t)g * 6 + k] : in1[(size_t)g * 8 + (k - 6)];
      Zt[row * SK + k] = v;
    }
  }
  __syncthreads();

  const bf16* W1t = W1p + (size_t)t * w1s;
  const bf16* W2t = W2p + (size_t)t * w2s;
  floatx4 acc[RT][2];
  #pragma unroll
  for (int rt = 0; rt < RT; rt++)
    #pragma unroll
    for (int c = 0; c < 2; c++) acc[rt][c] = (floatx4){0.f, 0.f, 0.f, 0.f};
  #pragma unroll
  for (int ks = 0; ks < KS1; ks++) {
    short8 bfr0 = *(const short8*)(W1t + (((size_t)(wave * 2 + 0) * KS1 + ks) * 64 + lane) * 8);
    short8 bfr1 = *(const short8*)(W1t + (((size_t)(wave * 2 + 1) * KS1 + ks) * 64 + lane) * 8);
    #pragma unroll
    for (int rt = 0; rt < RT; rt++) {
      short8 a = *(const short8*)(&Zt[(rt * 16 + colq) * SK + ks * 32 + quad * 8]);
      acc[rt][0] = __builtin_amdgcn_mfma_f32_16x16x32_bf16(a, bfr0, acc[rt][0], 0, 0, 0);
      acc[rt][1] = __builtin_amdgcn_mfma_f32_16x16x32_bf16(a, bfr1, acc[rt][1], 0, 0, 0);
    }
  }
  #pragma unroll
  for (int c = 0; c < 2; c++) {
    int col = wave * 32 + c * 16 + colq;
    float bv = b2f(b1v[t * b1s + col]);
    #pragma unroll
    for (int rt = 0; rt < RT; rt++)
      #pragma unroll
      for (int r = 0; r < 4; r++) {
        float v = acc[rt][c][r] + bv;
        Hid[(rt * 16 + quad * 4 + r) * HS + col] = __float2bfloat16(fmaxf(v, 0.f));
      }
  }
  __syncthreads();

  floatx4 acc2[RT][2];
  #pragma unroll
  for (int rt = 0; rt < RT; rt++)
    #pragma unroll
    for (int c = 0; c < 2; c++) acc2[rt][c] = (floatx4){0.f, 0.f, 0.f, 0.f};
  #pragma unroll
  for (int ks = 0; ks < 4; ks++) {
    short8 bfr0 = *(const short8*)(W2t + (((size_t)(wave * 2 + 0) * 4 + ks) * 64 + lane) * 8);
    short8 bfr1 = *(const short8*)(W2t + (((size_t)(wave * 2 + 1) * 4 + ks) * 64 + lane) * 8);
    #pragma unroll
    for (int rt = 0; rt < RT; rt++) {
      short8 a = *(const short8*)(&Hid[(rt * 16 + colq) * HS + ks * 32 + quad * 8]);
      acc2[rt][0] = __builtin_amdgcn_mfma_f32_16x16x32_bf16(a, bfr0, acc2[rt][0], 0, 0, 0);
      acc2[rt][1] = __builtin_amdgcn_mfma_f32_16x16x32_bf16(a, bfr1, acc2[rt][1], 0, 0, 0);
    }
  }
  if (DEC) {
    if (wave == 0 && colq < 4) {
      int isBf = flagp[0];
      float bv = b2f(b2v[t * b2s + colq]);
      #pragma unroll
      for (int rt = 0; rt < RT; rt++)
        #pragma unroll
        for (int r = 0; r < 4; r++) {
          int g = gIdx[rt * 16 + quad * 4 + r];
          if (g >= 0) {
            float v = acc2[rt][0][r] + bv;
            if (isBf) ((bf16*)outp)[(size_t)g * 4 + colq] = __float2bfloat16(v);
            else      ((float*)outp)[(size_t)g * 4 + colq] = v;
          }
        }
    }
  } else {
    #pragma unroll
    for (int c = 0; c < 2; c++) {
      int col = wave * 32 + c * 16 + colq;
      float bv = b2f(b2v[t * b2s + col]);
      #pragma unroll
      for (int rt = 0; rt < RT; rt++)
        #pragma unroll
        for (int r = 0; r < 4; r++) {
          int g = gIdx[rt * 16 + quad * 4 + r];
          if (g >= 0) ((bf16*)outp)[(size_t)g * HDIM + col] = __float2bfloat16(acc2[rt][c][r] + bv);
        }
    }
  }
}

// -------------------------------------------------- edge-encoder MLP (contiguous eaS)
template<int BM>
__global__ void __launch_bounds__(256) ee_kernel(
    const bf16* __restrict__ eaS,
    const bf16* __restrict__ W1p, const bf16* __restrict__ b1v,
    const bf16* __restrict__ W2p, const bf16* __restrict__ b2v,
    bf16* __restrict__ outp, int M) {
  constexpr int RT = BM / 16;
  constexpr int SK = 136;
  __shared__ bf16 Zt[BM * SK];
  const int tid = threadIdx.x;
  const int lane = tid & 63, wave = tid >> 6, colq = lane & 15, quad = lane >> 4;
  const int row0 = blockIdx.x * BM;

  for (int i = tid; i < BM * 4; i += 256) {
    int row = i >> 2, seg = i & 3;
    int gr = row0 + row;
    uint4 val = {0u, 0u, 0u, 0u};
    if (seg == 0 && gr < M) {
      uint2 v = *(const uint2*)(eaS + (size_t)gr * 4);
      val.x = v.x; val.y = v.y;
    }
    *(uint4*)(&Zt[row * SK + seg * 8]) = val;
  }
  __syncthreads();

  floatx4 acc[RT][2];
  #pragma unroll
  for (int rt = 0; rt < RT; rt++)
    #pragma unroll
    for (int c = 0; c < 2; c++) acc[rt][c] = (floatx4){0.f, 0.f, 0.f, 0.f};
  {
    short8 bfr0 = *(const short8*)(W1p + (((size_t)(wave * 2 + 0)) * 64 + lane) * 8);
    short8 bfr1 = *(const short8*)(W1p + (((size_t)(wave * 2 + 1)) * 64 + lane) * 8);
    #pragma unroll
    for (int rt = 0; rt < RT; rt++) {
      short8 a = *(const short8*)(&Zt[(rt * 16 + colq) * SK + quad * 8]);
      acc[rt][0] = __builtin_amdgcn_mfma_f32_16x16x32_bf16(a, bfr0, acc[rt][0], 0, 0, 0);
      acc[rt][1] = __builtin_amdgcn_mfma_f32_16x16x32_bf16(a, bfr1, acc[rt][1], 0, 0, 0);
    }
  }
  __syncthreads();
  #pragma unroll
  for (int c = 0; c < 2; c++) {
    int col = wave * 32 + c * 16 + colq;
    float bv = b2f(b1v[col]);
    #pragma unroll
    for (int rt = 0; rt < RT; rt++)
      #pragma unroll
      for (int r = 0; r < 4; r++)
        Zt[(rt * 16 + quad * 4 + r) * SK + col] =
            __float2bfloat16(fmaxf(acc[rt][c][r] + bv, 0.f));
  }
  __syncthreads();

  floatx4 acc2[RT][2];
  #pragma unroll
  for (int rt = 0; rt < RT; rt++)
    #pragma unroll
    for (int c = 0; c < 2; c++) acc2[rt][c] = (floatx4){0.f, 0.f, 0.f, 0.f};
  #pragma unroll
  for (int ks = 0; ks < 4; ks++) {
    short8 bfr0 = *(const short8*)(W2p + (((size_t)(wave * 2 + 0) * 4 + ks) * 64 + lane) * 8);
    short8 bfr1 = *(const short8*)(W2p + (((size_t)(wave * 2 + 1) * 4 + ks) * 64 + lane) * 8);
    #pragma unroll
    for (int rt = 0; rt < RT; rt++) {
      short8 a = *(const short8*)(&Zt[(rt * 16 + colq) * SK + ks * 32 + quad * 8]);
      acc2[rt][0] = __builtin_amdgcn_mfma_f32_16x16x32_bf16(a, bfr0, acc2[rt][0], 0, 0, 0);
      acc2[rt][1] = __builtin_amdgcn_mfma_f32_16x16x32_bf16(a, bfr1, acc2[rt][1], 0, 0, 0);
    }
  }
  #pragma unroll
  for (int c = 0; c < 2; c++) {
    int col = wave * 32 + c * 16 + colq;
    float bv = b2f(b2v[col]);
    #pragma unroll
    for (int rt = 0; rt < RT; rt++)
      #pragma unroll
      for (int r = 0; r < 4; r++) {
        int grow = row0 + rt * 16 + quad * 4 + r;
        if (grow < M)
          outp[(size_t)grow * HDIM + col] = __float2bfloat16(acc2[rt][c][r] + bv);
      }
  }
}

// ---------------------------------------------------------------- launcher
extern "C" void kernel_launch(void* const* d_in, const int* in_sizes, int n_in,
                              void* d_out, int out_size, void* d_ws, size_t ws_size,
                              hipStream_t stream) {
  const int* edge_index = (const int*)d_in[27];
  const int* node_types = (const int*)d_in[28];
  const int N = in_sizes[28];
  const int E = in_sizes[2] / 4;
  const int L = in_sizes[12] / HDIM;
  const int* srcI = edge_index;
  const int* dstI = edge_index + E;

  CanonDesc cd;
  int total = 0;
  for (int i = 0; i < NCANON; i++) { cd.src[i] = d_in[i]; cd.prefix[i] = total; total += in_sizes[i]; }
  cd.prefix[NCANON] = total;

  char* wsb = (char*)d_ws;
  size_t off = 0;
  auto alloc = [&](size_t bytes) -> void* {
    void* p = wsb + off;
    off += (bytes + 255) & ~(size_t)255;
    return p;
  };
  int*  flag      = (int*)alloc(256);
  bf16* arena     = (bf16*)alloc((size_t)total * 2);
  bf16* h_nodes   = (bf16*)alloc((size_t)N * HDIM * 2);
  bf16* h_edges   = (bf16*)alloc((size_t)E * HDIM * 2);
  float* m_node   = (float*)alloc((size_t)N * HDIM * 4);
  bf16* ysrcb     = (bf16*)alloc((size_t)N * HDIM * 2);
  bf16* ydstb     = (bf16*)alloc((size_t)N * HDIM * 2);
  bf16* eaS       = (bf16*)alloc((size_t)E * 4 * 2);
  int* counts     = (int*)alloc((size_t)N * 4);
  int* cursor     = (int*)alloc((size_t)N * 4);
  int* row_start  = (int*)alloc((size_t)(N + 1) * 4);
  int* bsum       = (int*)alloc(260 * 4);
  int* srcS       = (int*)alloc((size_t)E * 4);
  int* dstS       = (int*)alloc((size_t)E * 4);
  int* tsArr      = (int*)alloc(64);
  int* permT      = (int*)alloc((size_t)N * 4);
  bf16* eeW1p  = (bf16*)alloc(4096 * 2);
  bf16* eeW2p  = (bf16*)alloc(16384 * 2);
  bf16* encW1p = (bf16*)alloc(3 * 4096 * 2);
  bf16* encW2p = (bf16*)alloc(3 * 16384 * 2);
  bf16* decW1p = (bf16*)alloc(3 * 16384 * 2);
  bf16* decW2p = (bf16*)alloc(3 * 16384 * 2);
  bf16* euW1a  = (bf16*)alloc((size_t)L * 16384 * 2);
  bf16* euW1b  = (bf16*)alloc((size_t)L * 16384 * 2);
  bf16* euW1c  = (bf16*)alloc((size_t)L * 16384 * 2);
  bf16* euW2p  = (bf16*)alloc((size_t)L * 16384 * 2);
  bf16* nuW1p  = (bf16*)alloc((size_t)L * 32768 * 2);
  bf16* nuW2p  = (bf16*)alloc((size_t)L * 16384 * 2);
  bf16* fuW1p  = (bf16*)alloc((size_t)L * 16384 * 2);
  bf16* fuW2p  = (bf16*)alloc((size_t)L * 16384 * 2);

  const bf16* cX     = arena + cd.prefix[0];
  const bf16* cPE    = arena + cd.prefix[1];
  const bf16* cEA    = arena + cd.prefix[2];
  const bf16* cEncW1 = arena + cd.prefix[3];
  const bf16* cEncB1 = arena + cd.prefix[4];
  const bf16* cEncW2 = arena + cd.prefix[5];
  const bf16* cEncB2 = arena + cd.prefix[6];
  const bf16* cEeW1  = arena + cd.prefix[7];
  const bf16* cEeB1  = arena + cd.prefix[8];
  const bf16* cEeW2  = arena + cd.prefix[9];
  const bf16* cEeB2  = arena + cd.prefix[10];
  const bf16* cEuW1  = arena + cd.prefix[11];
  const bf16* cEuB1  = arena + cd.prefix[12];
  const bf16* cEuW2  = arena + cd.prefix[13];
  const bf16* cEuB2  = arena + cd.prefix[14];
  const bf16* cNuW1  = arena + cd.prefix[15];
  const bf16* cNuB1  = arena + cd.prefix[16];
  const bf16* cNuW2  = arena + cd.prefix[17];
  const bf16* cNuB2  = arena + cd.prefix[18];
  const bf16* cFuW1  = arena + cd.prefix[19];
  const bf16* cFuB1  = arena + cd.prefix[20];
  const bf16* cFuW2  = arena + cd.prefix[21];
  const bf16* cFuB2  = arena + cd.prefix[22];
  const bf16* cDecW1 = arena + cd.prefix[23];
  const bf16* cDecB1 = arena + cd.prefix[24];
  const bf16* cDecW2 = arena + cd.prefix[25];
  const bf16* cDecB2 = arena + cd.prefix[26];

  canon_kernel<<<(total + 255) / 256, 256, 0, stream>>>(
      cd, (const unsigned short*)d_in[0], flag, arena, total);

  hipMemsetAsync(counts, 0, (size_t)N * 4, stream);
  hipMemsetAsync(cursor, 0, (size_t)N * 4, stream);

  PackJobs PJ;
  int nj = 0;
  PJ.j[nj++] = {cEeW1, eeW1p, 4, 1, 128};
  PJ.j[nj++] = {cEeW2, eeW2p, 128, 4, 128};
  for (int l = 0; l < L; l++) {
    const bf16* w1 = cEuW1 + (size_t)l * 384 * HDIM;
    PJ.j[nj++] = {w1,                 euW1a + (size_t)l * 16384, 128, 4, 128};
    PJ.j[nj++] = {w1 + 128 * HDIM,    euW1b + (size_t)l * 16384, 128, 4, 128};
    PJ.j[nj++] = {w1 + 256 * HDIM,    euW1c + (size_t)l * 16384, 128, 4, 128};
    PJ.j[nj++] = {cEuW2 + (size_t)l * HDIM * HDIM, euW2p + (size_t)l * 16384, 128, 4, 128};
    PJ.j[nj++] = {cNuW1 + (size_t)l * 256 * HDIM,  nuW1p + (size_t)l * 32768, 256, 8, 128};
    PJ.j[nj++] = {cNuW2 + (size_t)l * HDIM * HDIM, nuW2p + (size_t)l * 16384, 128, 4, 128};
    PJ.j[nj++] = {cFuW1 + (size_t)l * HDIM * HDIM, fuW1p + (size_t)l * 16384, 128, 4, 128};
    PJ.j[nj++] = {cFuW2 + (size_t)l * HDIM * HDIM, fuW2p + (size_t)l * 16384, 128, 4, 128};
  }
  for (int t = 0; t < 3; t++) {
    PJ.j[nj++] = {cEncW1 + (size_t)t * 14 * HDIM,   encW1p + (size_t)t * 4096, 14, 1, 128};
    PJ.j[nj++] = {cEncW2 + (size_t)t * HDIM * HDIM, encW2p + (size_t)t * 16384, 128, 4, 128};
    PJ.j[nj++] = {cDecW1 + (size_t)t * HDIM * HDIM, decW1p + (size_t)t * 16384, 128, 4, 128};
    PJ.j[nj++] = {cDecW2 + (size_t)t * HDIM * 4,    decW2p + (size_t)t * 16384, 128, 4, 4};
  }
  pack_all_kernel<<<dim3(16, nj), 256, 0, stream>>>(PJ);

  // CSR (dst-sorted edges) + permuted edge_attr
  int nb = (N + 255) / 256;
  hist_kernel<<<(E + 255) / 256, 256, 0, stream>>>(dstI, counts, E);
  scan1_kernel<<<nb, 256, 0, stream>>>(counts, bsum, N);
  scan2_kernel<<<1, 64, 0, stream>>>(bsum, nb);
  scan3_kernel<<<nb, 256, 0, stream>>>(counts, bsum, row_start, N, nb);
  scatter_kernel<<<(E + 255) / 256, 256, 0, stream>>>(srcI, dstI, row_start, cursor,
                                                      cEA, eaS, srcS, dstS, E);
  tsort_kernel<<<1, 1024, 0, stream>>>(node_types, tsArr, permT, N);

  int ngrid64 = (N + 63) / 64;
  typed_kernel<1, false><<<dim3(ngrid64, 3), 256, 0, stream>>>(
      cX, cPE, permT, tsArr, flag, encW1p, 4096, cEncB1, HDIM,
      encW2p, 16384, cEncB2, HDIM, h_nodes);

  int egrid32  = (E + 31) / 32;
  int egrid128 = (E + 127) / 128;

  ee_kernel<128><<<egrid128, 256, 0, stream>>>(
      eaS, eeW1p, cEeB1, eeW2p, cEeB2, h_edges, E);

  for (int l = 0; l < L; l++) {
    if (l == 0) {
      // layer 0: Y from h_nodes (also zeroes m_node)
      ygemm_kernel<<<dim3(ngrid64, 2), 256, 0, stream>>>(
          h_nodes, euW1a, euW1b, ysrcb, ydstb, m_node, N);
    }
    if (l + 1 < L) {
      eu_kernel<32, true><<<egrid32, 256, 0, stream>>>(
          h_edges, ysrcb, ydstb, srcS, dstS,
          euW1c + (size_t)l * 16384, cEuB1 + l * HDIM,
          euW2p + (size_t)l * 16384, cEuB2 + l * HDIM, h_edges, m_node, E);
    } else {
      eu_kernel<32, false><<<egrid32, 256, 0, stream>>>(
          h_edges, ysrcb, ydstb, srcS, dstS,
          euW1c + (size_t)l * 16384, cEuB1 + l * HDIM,
          euW2p + (size_t)l * 16384, cEuB2 + l * HDIM, h_edges, m_node, E);
    }
    bool hasNext = (l + 1 < L);
    node_kernel<<<ngrid64, 256, 0, stream>>>(
        h_nodes, m_node,
        nuW1p + (size_t)l * 32768, cNuB1 + l * HDIM,
        nuW2p + (size_t)l * 16384, cNuB2 + l * HDIM,
        fuW1p + (size_t)l * 16384, cFuB1 + l * HDIM,
        fuW2p + (size_t)l * 16384, cFuB2 + l * HDIM,
        hasNext ? euW1a + (size_t)(l + 1) * 16384 : nullptr,
        hasNext ? euW1b + (size_t)(l + 1) * 16384 : nullptr,
        ysrcb, ydstb, h_nodes, N);
  }

  typed_kernel<4, true><<<dim3(ngrid64, 3), 256, 0, stream>>>(
      h_nodes, nullptr, permT, tsArr, flag, decW1p, 16384, cDecB1, HDIM,
      decW2p, 16384, cDecB2, 4, d_out);
  (void)n_in; (void)ws_size;
}

// Round 12
// 474.648 us; speedup vs baseline: 1.2476x; 1.0033x over previous
//
#include <hip/hip_runtime.h>
#include <hip/hip_bf16.h>

typedef __hip_bfloat16 bf16;
typedef __attribute__((ext_vector_type(8))) short short8;   // 8 bf16 frag
typedef __attribute__((ext_vector_type(4))) float floatx4;  // MFMA C/D frag

#define HDIM 128
#define NCANON 27

__device__ __forceinline__ float b2f(bf16 v) { return __bfloat162float(v); }
__device__ __forceinline__ float s2f(short s) {
  return __uint_as_float(((unsigned int)(unsigned short)s) << 16);
}
__device__ __forceinline__ short f2s(float f) {
  return (short)__bfloat16_as_ushort(__float2bfloat16(f));
}

struct CanonDesc {
  const void* src[NCANON];
  int prefix[NCANON + 1];
};

// ---- canon + inlined dtype detect + zero-fill of counts/cursor (tail blocks)
__global__ void canon_kernel(CanonDesc d, const unsigned short* __restrict__ xraw,
                             int* __restrict__ flagOut, bf16* __restrict__ out, int total,
                             int canonBlocks, uint4* __restrict__ zbase, int zquads) {
  int tid = threadIdx.x;
  if (blockIdx.x >= canonBlocks) {
    int i = (blockIdx.x - canonBlocks) * 256 + tid;
    if (i < zquads) { uint4 z = {0u, 0u, 0u, 0u}; zbase[i] = z; }
    return;
  }
  __shared__ int sflag;
  if (tid < 64) {
    unsigned short u = xraw[2 * tid];
    int e = (u >> 7) & 0xFF;
    int ok = (u == 0) || (e >= 100 && e <= 140);
    unsigned long long m = __ballot(ok);
    if (tid == 0) sflag = (__popcll(m) >= 48) ? 1 : 0;
  }
  __syncthreads();
  int isBf = sflag;
  if (blockIdx.x == 0 && tid == 0) flagOut[0] = isBf;
  int t = blockIdx.x * 256 + tid;
  if (t >= total) return;
  int lo = 0, hi = NCANON;
  while (lo + 1 < hi) { int mid = (lo + hi) >> 1; if (d.prefix[mid] <= t) lo = mid; else hi = mid; }
  int off = t - d.prefix[lo];
  out[t] = isBf ? ((const bf16*)d.src[lo])[off]
                : __float2bfloat16(((const float*)d.src[lo])[off]);
}

// ---------------- hist (dst histogram) + tsort (type counting sort), one dispatch
__global__ void __launch_bounds__(1024) hist_tsort_kernel(
    const int* __restrict__ dst, int* __restrict__ cnt, int E, int hb,
    const int* __restrict__ types, int* __restrict__ ts, int* __restrict__ perm, int n) {
  if (blockIdx.x < hb) {
    int e = blockIdx.x * 1024 + threadIdx.x;
    if (e < E) atomicAdd(&cnt[dst[e]], 1);
    return;
  }
  // ---- tsort body (single block, 1024 threads)
  __shared__ int wc[16][3];
  __shared__ int base[3];
  int tid = threadIdx.x, lane = tid & 63, wave = tid >> 6;
  int c0 = 0, c1 = 0, c2 = 0;
  for (int i = tid; i < n; i += 1024) {
    int t = types[i];
    c0 += (t == 0); c1 += (t == 1); c2 += (t == 2);
  }
  #pragma unroll
  for (int d = 32; d; d >>= 1) {
    c0 += __shfl_down(c0, d); c1 += __shfl_down(c1, d); c2 += __shfl_down(c2, d);
  }
  if (lane == 0) { wc[wave][0] = c0; wc[wave][1] = c1; wc[wave][2] = c2; }
  __syncthreads();
  if (tid == 0) {
    int t0 = 0, t1 = 0;
    for (int w = 0; w < 16; w++) { t0 += wc[w][0]; t1 += wc[w][1]; }
    ts[0] = 0; ts[1] = t0; ts[2] = t0 + t1; ts[3] = n;
    base[0] = 0; base[1] = t0; base[2] = t0 + t1;
  }
  __syncthreads();
  for (int i0 = 0; i0 < n; i0 += 1024) {
    int i = i0 + tid;
    int t = (i < n) ? types[i] : -1;
    unsigned long long m0 = __ballot(t == 0);
    unsigned long long m1 = __ballot(t == 1);
    unsigned long long m2 = __ballot(t == 2);
    if (lane == 0) { wc[wave][0] = __popcll(m0); wc[wave][1] = __popcll(m1); wc[wave][2] = __popcll(m2); }
    __syncthreads();
    if (i < n) {
      unsigned long long mt = (t == 0) ? m0 : ((t == 1) ? m1 : m2);
      unsigned long long below = (lane == 0) ? 0ull : ((1ull << lane) - 1ull);
      int r = __popcll(mt & below);
      int woff = 0;
      for (int w = 0; w < wave; w++) woff += wc[w][t];
      perm[base[t] + woff + r] = i;
    }
    __syncthreads();
    if (tid == 0) {
      int a0 = 0, a1 = 0, a2 = 0;
      for (int w = 0; w < 16; w++) { a0 += wc[w][0]; a1 += wc[w][1]; a2 += wc[w][2]; }
      base[0] += a0; base[1] += a1; base[2] += a2;
    }
    __syncthreads();
  }
}

__global__ void scan1_kernel(const int* __restrict__ cnt, int* __restrict__ bsum, int n) {
  int tid = threadIdx.x, lane = tid & 63, wave = tid >> 6;
  int i = blockIdx.x * 256 + tid;
  int v = (i < n) ? cnt[i] : 0;
  #pragma unroll
  for (int d = 32; d; d >>= 1) v += __shfl_down(v, d);
  __shared__ int ws[4];
  if (lane == 0) ws[wave] = v;
  __syncthreads();
  if (tid == 0) bsum[blockIdx.x] = ws[0] + ws[1] + ws[2] + ws[3];
}

__global__ void scan2_kernel(int* __restrict__ bsum, int nb) {   // nb <= 128; 64 threads
  int lane = threadIdx.x;
  int a0 = (lane < nb) ? bsum[lane] : 0;
  int b0 = (64 + lane < nb) ? bsum[64 + lane] : 0;
  int a = a0, b = b0;
  #pragma unroll
  for (int d = 1; d < 64; d <<= 1) { int t = __shfl_up(a, d); if (lane >= d) a += t; }
  int totA = __shfl(a, 63);
  #pragma unroll
  for (int d = 1; d < 64; d <<= 1) { int t = __shfl_up(b, d); if (lane >= d) b += t; }
  int totB = __shfl(b, 63);
  if (lane < nb) bsum[lane] = a - a0;
  if (64 + lane < nb) bsum[64 + lane] = b - b0 + totA;
  if (lane == 0) bsum[nb] = totA + totB;
}

__global__ void scan3_kernel(const int* __restrict__ cnt, const int* __restrict__ bsum,
                             int* __restrict__ row_start, int n, int nb) {
  __shared__ int sh[256];
  int tid = threadIdx.x;
  int i = blockIdx.x * 256 + tid;
  int v = (i < n) ? cnt[i] : 0;
  sh[tid] = v;
  __syncthreads();
  #pragma unroll
  for (int off = 1; off < 256; off <<= 1) {
    int t = (tid >= off) ? sh[tid - off] : 0;
    __syncthreads();
    sh[tid] += t;
    __syncthreads();
  }
  if (i < n) row_start[i] = bsum[blockIdx.x] + sh[tid] - v;
  if (blockIdx.x == 0 && tid == 0) row_start[n] = bsum[nb];
}

// scatter: permutes edge_attr into dst-sorted order too
__global__ void scatter_kernel(const int* __restrict__ src, const int* __restrict__ dst,
                               const int* __restrict__ row_start, int* __restrict__ cursor,
                               const bf16* __restrict__ ea, bf16* __restrict__ eaS,
                               int* __restrict__ srcS, int* __restrict__ dstS, int E) {
  int e = blockIdx.x * 256 + threadIdx.x;
  if (e < E) {
    int d = dst[e];
    int pos = row_start[d] + atomicAdd(&cursor[d], 1);
    srcS[pos] = src[e];
    dstS[pos] = d;
    *(uint2*)(eaS + (size_t)pos * 4) = *(const uint2*)(ea + (size_t)e * 4);
  }
}

// -------------------------------------------------- fused weight pre-pack (B-frag order)
struct PackJob { const bf16* src; bf16* dst; int Ksrc; int KS; int srcCols; };
struct PackJobs { PackJob j[40]; };

__global__ void pack_all_kernel(PackJobs J) {
  PackJob job = J.j[blockIdx.y];
  int idx = blockIdx.x * 256 + threadIdx.x;
  int total = 8 * job.KS * 64;
  if (idx >= total) return;
  int lane = idx & 63;
  int ks = (idx >> 6) % job.KS;
  int ct = idx / (64 * job.KS);
  bf16* o = job.dst + (size_t)idx * 8;
  int ncol = ct * 16 + (lane & 15);
  int kb = ks * 32 + ((lane >> 4) & 3) * 8;
  #pragma unroll
  for (int jj = 0; jj < 8; jj++) {
    int k = kb + jj;
    o[jj] = (k < job.Ksrc && ncol < job.srcCols)
              ? job.src[(size_t)k * job.srcCols + ncol] : __float2bfloat16(0.f);
  }
}

// ------------- per-node Y = h @ W1a / W1b (bf16 out) + zero m_node (layer 0 only)
__global__ void __launch_bounds__(256) ygemm_kernel(
    const bf16* __restrict__ X,
    const bf16* __restrict__ WpA, const bf16* __restrict__ WpB,
    bf16* __restrict__ outA, bf16* __restrict__ outB,
    float* __restrict__ mnode, int M) {
  const bf16* Wp = blockIdx.y ? WpB : WpA;
  bf16* outp = blockIdx.y ? outB : outA;
  constexpr int BM = 64, RT = 4, SK = 136;
  __shared__ bf16 Zt[BM * SK];
  const int tid = threadIdx.x;
  const int lane = tid & 63, wave = tid >> 6, colq = lane & 15, quad = lane >> 4;
  const int row0 = blockIdx.x * BM;
  if (blockIdx.y == 0) {
    float4 z = {0.f, 0.f, 0.f, 0.f};
    for (int i = tid; i < BM * 32; i += 256) {
      int row = i >> 5, q = i & 31;
      int gr = row0 + row;
      if (gr < M) *(float4*)(mnode + (size_t)gr * HDIM + q * 4) = z;
    }
  }
  {
    int row = tid >> 2, sub = tid & 3;
    int gr = row0 + row;
    bool ok = gr < M;
    #pragma unroll
    for (int j = 0; j < 4; j++) {
      int seg = j * 4 + sub;
      uint4 v = {0u, 0u, 0u, 0u};
      if (ok) v = *(const uint4*)(X + (size_t)gr * HDIM + seg * 8);
      *(uint4*)(&Zt[row * SK + seg * 8]) = v;
    }
  }
  __syncthreads();
  floatx4 acc[RT][2];
  #pragma unroll
  for (int rt = 0; rt < RT; rt++)
    #pragma unroll
    for (int c = 0; c < 2; c++) acc[rt][c] = (floatx4){0.f, 0.f, 0.f, 0.f};
  #pragma unroll
  for (int ks = 0; ks < 4; ks++) {
    short8 bfr0 = *(const short8*)(Wp + (((size_t)(wave * 2 + 0) * 4 + ks) * 64 + lane) * 8);
    short8 bfr1 = *(const short8*)(Wp + (((size_t)(wave * 2 + 1) * 4 + ks) * 64 + lane) * 8);
    #pragma unroll
    for (int rt = 0; rt < RT; rt++) {
      short8 a = *(const short8*)(&Zt[(rt * 16 + colq) * SK + ks * 32 + quad * 8]);
      acc[rt][0] = __builtin_amdgcn_mfma_f32_16x16x32_bf16(a, bfr0, acc[rt][0], 0, 0, 0);
      acc[rt][1] = __builtin_amdgcn_mfma_f32_16x16x32_bf16(a, bfr1, acc[rt][1], 0, 0, 0);
    }
  }
  #pragma unroll
  for (int c = 0; c < 2; c++) {
    int col = wave * 32 + c * 16 + colq;
    #pragma unroll
    for (int rt = 0; rt < RT; rt++)
      #pragma unroll
      for (int r = 0; r < 4; r++) {
        int grow = row0 + rt * 16 + quad * 4 + r;
        if (grow < M) outp[(size_t)grow * HDIM + col] = __float2bfloat16(acc[rt][c][r]);
      }
  }
}

// ----------------------- edge-update + fused dst-segment aggregation
template<int BM, bool WRITE_HE>
__global__ void __launch_bounds__(256) eu_kernel(
    const bf16* __restrict__ he, const bf16* __restrict__ ysrc, const bf16* __restrict__ ydst,
    const int* __restrict__ srcS, const int* __restrict__ dstS,
    const bf16* __restrict__ W1p, const bf16* __restrict__ b1v,
    const bf16* __restrict__ W2p, const bf16* __restrict__ b2v,
    bf16* __restrict__ outp, float* __restrict__ mnode, int M) {
  constexpr int RT = BM / 16;
  constexpr int SK = 264;
  __shared__ bf16 Zt[BM * SK];
  __shared__ int dstLds[BM];
  const int tid = threadIdx.x;
  const int lane = tid & 63, wave = tid >> 6, colq = lane & 15, quad = lane >> 4;
  const int row0 = blockIdx.x * BM;
  constexpr int TPR = 256 / BM;
  {
    int row = tid / TPR, sub = tid % TPR;
    int gr = row0 + row;
    bool ok = gr < M;
    int g0 = ok ? srcS[gr] : 0;
    int g1 = ok ? dstS[gr] : 0;
    if (sub == 0) dstLds[row] = ok ? g1 : -1;
    #pragma unroll
    for (int j = 0; j < 32 / TPR; j++) {
      int c = j * TPR + sub;
      int part = c >> 4, seg = c & 15;
      if (part == 0) {
        short8 o = {0, 0, 0, 0, 0, 0, 0, 0};
        if (ok) {
          short8 a = *(const short8*)(ysrc + (size_t)g0 * HDIM + seg * 8);
          short8 b = *(const short8*)(ydst + (size_t)g1 * HDIM + seg * 8);
          #pragma unroll
          for (int k = 0; k < 8; k++) o[k] = f2s(s2f(a[k]) + s2f(b[k]));
        }
        *(short8*)(&Zt[row * SK + seg * 8]) = o;
      } else {
        uint4 v = {0u, 0u, 0u, 0u};
        if (ok) v = *(const uint4*)(he + (size_t)gr * HDIM + seg * 8);
        *(uint4*)(&Zt[row * SK + 128 + seg * 8]) = v;
      }
    }
  }
  __syncthreads();

  floatx4 acc[RT][2];
  #pragma unroll
  for (int rt = 0; rt < RT; rt++)
    #pragma unroll
    for (int c = 0; c < 2; c++) acc[rt][c] = (floatx4){0.f, 0.f, 0.f, 0.f};
  #pragma unroll
  for (int ks = 0; ks < 4; ks++) {
    short8 bfr0 = *(const short8*)(W1p + (((size_t)(wave * 2 + 0) * 4 + ks) * 64 + lane) * 8);
    short8 bfr1 = *(const short8*)(W1p + (((size_t)(wave * 2 + 1) * 4 + ks) * 64 + lane) * 8);
    #pragma unroll
    for (int rt = 0; rt < RT; rt++) {
      short8 a = *(const short8*)(&Zt[(rt * 16 + colq) * SK + 128 + ks * 32 + quad * 8]);
      acc[rt][0] = __builtin_amdgcn_mfma_f32_16x16x32_bf16(a, bfr0, acc[rt][0], 0, 0, 0);
      acc[rt][1] = __builtin_amdgcn_mfma_f32_16x16x32_bf16(a, bfr1, acc[rt][1], 0, 0, 0);
    }
  }
  #pragma unroll
  for (int c = 0; c < 2; c++) {
    int col = wave * 32 + c * 16 + colq;
    float bv = b2f(b1v[col]);
    #pragma unroll
    for (int rt = 0; rt < RT; rt++)
      #pragma unroll
      for (int r = 0; r < 4; r++) {
        int lrow = rt * 16 + quad * 4 + r;
        float v = acc[rt][c][r] + bv + b2f(Zt[lrow * SK + col]);
        Zt[lrow * SK + col] = __float2bfloat16(fmaxf(v, 0.f));
      }
  }
  __syncthreads();

  floatx4 acc2[RT][2];
  #pragma unroll
  for (int rt = 0; rt < RT; rt++)
    #pragma unroll
    for (int c = 0; c < 2; c++) acc2[rt][c] = (floatx4){0.f, 0.f, 0.f, 0.f};
  #pragma unroll
  for (int ks = 0; ks < 4; ks++) {
    short8 bfr0 = *(const short8*)(W2p + (((size_t)(wave * 2 + 0) * 4 + ks) * 64 + lane) * 8);
    short8 bfr1 = *(const short8*)(W2p + (((size_t)(wave * 2 + 1) * 4 + ks) * 64 + lane) * 8);
    #pragma unroll
    for (int rt = 0; rt < RT; rt++) {
      short8 a = *(const short8*)(&Zt[(rt * 16 + colq) * SK + ks * 32 + quad * 8]);
      acc2[rt][0] = __builtin_amdgcn_mfma_f32_16x16x32_bf16(a, bfr0, acc2[rt][0], 0, 0, 0);
      acc2[rt][1] = __builtin_amdgcn_mfma_f32_16x16x32_bf16(a, bfr1, acc2[rt][1], 0, 0, 0);
    }
  }
  #pragma unroll
  for (int c = 0; c < 2; c++) {
    int col = wave * 32 + c * 16 + colq;
    float bv = b2f(b2v[col]);
    #pragma unroll
    for (int rt = 0; rt < RT; rt++)
      #pragma unroll
      for (int r = 0; r < 4; r++) {
        int lrow = rt * 16 + quad * 4 + r;
        int grow = row0 + lrow;
        float v = acc2[rt][c][r] + bv + b2f(Zt[lrow * SK + 128 + col]);
        bf16 vb = __float2bfloat16(v);
        Zt[lrow * SK + 128 + col] = vb;
        if (WRITE_HE && grow < M) outp[(size_t)grow * HDIM + col] = vb;
      }
  }
  __syncthreads();

  {
    int col = tid & 127;
    int half = tid >> 7;
    int rbeg = half * (BM / 2), rend = rbeg + (BM / 2);
    float s = 0.f;
    int runDst = dstLds[rbeg];
    bool touchStart = true;
    for (int r = rbeg; r < rend; r++) {
      int d = dstLds[r];
      if (d != runDst) {
        if (runDst >= 0) {
          float* mp = &mnode[(size_t)runDst * HDIM + col];
          if (touchStart) atomicAdd(mp, s); else *mp = s;
        }
        runDst = d; s = 0.f; touchStart = false;
      }
      s += b2f(Zt[r * SK + 128 + col]);
    }
    if (runDst >= 0) atomicAdd(&mnode[(size_t)runDst * HDIM + col], s);
  }
}

// ----------------------- fused node update + fusion MLP (+ next-layer Y emit)
__global__ void __launch_bounds__(256) node_kernel(
    const bf16* __restrict__ h_nodes, float* __restrict__ mnode,
    const bf16* __restrict__ nuW1, const bf16* __restrict__ nuB1,
    const bf16* __restrict__ nuW2, const bf16* __restrict__ nuB2,
    const bf16* __restrict__ fuW1, const bf16* __restrict__ fuB1,
    const bf16* __restrict__ fuW2, const bf16* __restrict__ fuB2,
    const bf16* __restrict__ yW1a, const bf16* __restrict__ yW1b,
    bf16* __restrict__ ysA, bf16* __restrict__ ysB,
    bf16* __restrict__ outp, int M) {
  constexpr int BM = 64, RT = 4, SK = 264;
  __shared__ bf16 Zt[BM * SK];
  const int tid = threadIdx.x;
  const int lane = tid & 63, wave = tid >> 6, colq = lane & 15, quad = lane >> 4;
  const int row0 = blockIdx.x * BM;
  {
    int row = tid >> 2, sub = tid & 3;
    int gr = row0 + row;
    bool ok = gr < M;
    float4 z4 = {0.f, 0.f, 0.f, 0.f};
    #pragma unroll
    for (int j = 0; j < 8; j++) {
      int c = j * 4 + sub;
      int part = c >> 4, seg = c & 15;
      if (part == 0) {
        uint4 v = {0u, 0u, 0u, 0u};
        if (ok) v = *(const uint4*)(h_nodes + (size_t)gr * HDIM + seg * 8);
        *(uint4*)(&Zt[row * SK + seg * 8]) = v;
      } else {
        short8 o = {0, 0, 0, 0, 0, 0, 0, 0};
        if (ok) {
          float* mp = mnode + (size_t)gr * HDIM + seg * 8;
          #pragma unroll
          for (int k = 0; k < 8; k++) o[k] = f2s(mp[k]);
          if (yW1a) { *(float4*)(mp) = z4; *(float4*)(mp + 4) = z4; }
        }
        *(short8*)(&Zt[row * SK + 128 + seg * 8]) = o;
      }
    }
  }
  __syncthreads();

  floatx4 acc[RT][2];
  #pragma unroll
  for (int rt = 0; rt < RT; rt++)
    #pragma unroll
    for (int c = 0; c < 2; c++) acc[rt][c] = (floatx4){0.f, 0.f, 0.f, 0.f};
  #pragma unroll
  for (int ks = 0; ks < 8; ks++) {
    short8 bfr0 = *(const short8*)(nuW1 + (((size_t)(wave * 2 + 0) * 8 + ks) * 64 + lane) * 8);
    short8 bfr1 = *(const short8*)(nuW1 + (((size_t)(wave * 2 + 1) * 8 + ks) * 64 + lane) * 8);
    #pragma unroll
    for (int rt = 0; rt < RT; rt++) {
      short8 a = *(const short8*)(&Zt[(rt * 16 + colq) * SK + ks * 32 + quad * 8]);
      acc[rt][0] = __builtin_amdgcn_mfma_f32_16x16x32_bf16(a, bfr0, acc[rt][0], 0, 0, 0);
      acc[rt][1] = __builtin_amdgcn_mfma_f32_16x16x32_bf16(a, bfr1, acc[rt][1], 0, 0, 0);
    }
  }
  __syncthreads();
  #pragma unroll
  for (int c = 0; c < 2; c++) {
    int col = wave * 32 + c * 16 + colq;
    float bv = b2f(nuB1[col]);
    #pragma unroll
    for (int rt = 0; rt < RT; rt++)
      #pragma unroll
      for (int r = 0; r < 4; r++)
        Zt[(rt * 16 + quad * 4 + r) * SK + 128 + col] =
            __float2bfloat16(fmaxf(acc[rt][c][r] + bv, 0.f));
  }
  __syncthreads();

  #pragma unroll
  for (int rt = 0; rt < RT; rt++)
    #pragma unroll
    for (int c = 0; c < 2; c++) acc[rt][c] = (floatx4){0.f, 0.f, 0.f, 0.f};
  #pragma unroll
  for (int ks = 0; ks < 4; ks++) {
    short8 bfr0 = *(const short8*)(nuW2 + (((size_t)(wave * 2 + 0) * 4 + ks) * 64 + lane) * 8);
    short8 bfr1 = *(const short8*)(nuW2 + (((size_t)(wave * 2 + 1) * 4 + ks) * 64 + lane) * 8);
    #pragma unroll
    for (int rt = 0; rt < RT; rt++) {
      short8 a = *(const short8*)(&Zt[(rt * 16 + colq) * SK + 128 + ks * 32 + quad * 8]);
      acc[rt][0] = __builtin_amdgcn_mfma_f32_16x16x32_bf16(a, bfr0, acc[rt][0], 0, 0, 0);
      acc[rt][1] = __builtin_amdgcn_mfma_f32_16x16x32_bf16(a, bfr1, acc[rt][1], 0, 0, 0);
    }
  }
  #pragma unroll
  for (int c = 0; c < 2; c++) {
    int col = wave * 32 + c * 16 + colq;
    float bv = b2f(nuB2[col]);
    #pragma unroll
    for (int rt = 0; rt < RT; rt++)
      #pragma unroll
      for (int r = 0; r < 4; r++) {
        int lrow = rt * 16 + quad * 4 + r;
        float v = acc[rt][c][r] + bv + b2f(Zt[lrow * SK + col]);
        Zt[lrow * SK + col] = __float2bfloat16(v);
      }
  }
  __syncthreads();

  #pragma unroll
  for (int rt = 0; rt < RT; rt++)
    #pragma unroll
    for (int c = 0; c < 2; c++) acc[rt][c] = (floatx4){0.f, 0.f, 0.f, 0.f};
  #pragma unroll
  for (int ks = 0; ks < 4; ks++) {
    short8 bfr0 = *(const short8*)(fuW1 + (((size_t)(wave * 2 + 0) * 4 + ks) * 64 + lane) * 8);
    short8 bfr1 = *(const short8*)(fuW1 + (((size_t)(wave * 2 + 1) * 4 + ks) * 64 + lane) * 8);
    #pragma unroll
    for (int rt = 0; rt < RT; rt++) {
      short8 a = *(const short8*)(&Zt[(rt * 16 + colq) * SK + ks * 32 + quad * 8]);
      acc[rt][0] = __builtin_amdgcn_mfma_f32_16x16x32_bf16(a, bfr0, acc[rt][0], 0, 0, 0);
      acc[rt][1] = __builtin_amdgcn_mfma_f32_16x16x32_bf16(a, bfr1, acc[rt][1], 0, 0, 0);
    }
  }
  #pragma unroll
  for (int c = 0; c < 2; c++) {
    int col = wave * 32 + c * 16 + colq;
    float bv = b2f(fuB1[col]);
    #pragma unroll
    for (int rt = 0; rt < RT; rt++)
      #pragma unroll
      for (int r = 0; r < 4; r++)
        Zt[(rt * 16 + quad * 4 + r) * SK + 128 + col] =
            __float2bfloat16(fmaxf(acc[rt][c][r] + bv, 0.f));
  }
  __syncthreads();

  #pragma unroll
  for (int rt = 0; rt < RT; rt++)
    #pragma unroll
    for (int c = 0; c < 2; c++) acc[rt][c] = (floatx4){0.f, 0.f, 0.f, 0.f};
  #pragma unroll
  for (int ks = 0; ks < 4; ks++) {
    short8 bfr0 = *(const short8*)(fuW2 + (((size_t)(wave * 2 + 0) * 4 + ks) * 64 + lane) * 8);
    short8 bfr1 = *(const short8*)(fuW2 + (((size_t)(wave * 2 + 1) * 4 + ks) * 64 + lane) * 8);
    #pragma unroll
    for (int rt = 0; rt < RT; rt++) {
      short8 a = *(const short8*)(&Zt[(rt * 16 + colq) * SK + 128 + ks * 32 + quad * 8]);
      acc[rt][0] = __builtin_amdgcn_mfma_f32_16x16x32_bf16(a, bfr0, acc[rt][0], 0, 0, 0);
      acc[rt][1] = __builtin_amdgcn_mfma_f32_16x16x32_bf16(a, bfr1, acc[rt][1], 0, 0, 0);
    }
  }
  #pragma unroll
  for (int c = 0; c < 2; c++) {
    int col = wave * 32 + c * 16 + colq;
    float bv = b2f(fuB2[col]);
    #pragma unroll
    for (int rt = 0; rt < RT; rt++)
      #pragma unroll
      for (int r = 0; r < 4; r++) {
        int lrow = rt * 16 + quad * 4 + r;
        int grow = row0 + lrow;
        bf16 hb = __float2bfloat16(acc[rt][c][r] + bv);
        Zt[lrow * SK + col] = hb;
        if (grow < M) outp[(size_t)grow * HDIM + col] = hb;
      }
  }
  if (!yW1a) return;
  __syncthreads();

  #pragma unroll
  for (int which = 0; which < 2; which++) {
    const bf16* Wp = which ? yW1b : yW1a;
    bf16* outy = which ? ysB : ysA;
    #pragma unroll
    for (int rt = 0; rt < RT; rt++)
      #pragma unroll
      for (int c = 0; c < 2; c++) acc[rt][c] = (floatx4){0.f, 0.f, 0.f, 0.f};
    #pragma unroll
    for (int ks = 0; ks < 4; ks++) {
      short8 bfr0 = *(const short8*)(Wp + (((size_t)(wave * 2 + 0) * 4 + ks) * 64 + lane) * 8);
      short8 bfr1 = *(const short8*)(Wp + (((size_t)(wave * 2 + 1) * 4 + ks) * 64 + lane) * 8);
      #pragma unroll
      for (int rt = 0; rt < RT; rt++) {
        short8 a = *(const short8*)(&Zt[(rt * 16 + colq) * SK + ks * 32 + quad * 8]);
        acc[rt][0] = __builtin_amdgcn_mfma_f32_16x16x32_bf16(a, bfr0, acc[rt][0], 0, 0, 0);
        acc[rt][1] = __builtin_amdgcn_mfma_f32_16x16x32_bf16(a, bfr1, acc[rt][1], 0, 0, 0);
      }
    }
    #pragma unroll
    for (int c = 0; c < 2; c++) {
      int col = wave * 32 + c * 16 + colq;
      #pragma unroll
      for (int rt = 0; rt < RT; rt++)
        #pragma unroll
        for (int r = 0; r < 4; r++) {
          int grow = row0 + rt * 16 + quad * 4 + r;
          if (grow < M) outy[(size_t)grow * HDIM + col] = __float2bfloat16(acc[rt][c][r]);
        }
    }
  }
}

// --------------- fused encoder (type-sorted) + edge-encoder, one dispatch
__global__ void __launch_bounds__(256) encee_kernel(
    int eeBlocks, int ngrid64,
    const bf16* __restrict__ eaS,
    const bf16* __restrict__ eeW1, const bf16* __restrict__ eeB1,
    const bf16* __restrict__ eeW2, const bf16* __restrict__ eeB2,
    bf16* __restrict__ h_edges, int E,
    const bf16* __restrict__ x, const bf16* __restrict__ pe,
    const int* __restrict__ perm, const int* __restrict__ ts,
    const bf16* __restrict__ encW1, const bf16* __restrict__ encB1,
    const bf16* __restrict__ encW2, const bf16* __restrict__ encB2,
    bf16* __restrict__ h_nodes) {
  __shared__ bf16 smem[128 * 136];   // ee: Zt[128*136]; enc: Zt[64*40] + Hid[64*136]
  __shared__ int gIdx[64];
  const int tid = threadIdx.x;
  const int lane = tid & 63, wave = tid >> 6, colq = lane & 15, quad = lane >> 4;

  if (blockIdx.x < eeBlocks) {
    // ---------------- ee body: BM=128
    constexpr int BM = 128, RT = 8, SK = 136;
    bf16* Zt = smem;
    const int row0 = blockIdx.x * BM;
    for (int i = tid; i < BM * 4; i += 256) {
      int row = i >> 2, seg = i & 3;
      int gr = row0 + row;
      uint4 val = {0u, 0u, 0u, 0u};
      if (seg == 0 && gr < E) {
        uint2 v = *(const uint2*)(eaS + (size_t)gr * 4);
        val.x = v.x; val.y = v.y;
      }
      *(uint4*)(&Zt[row * SK + seg * 8]) = val;
    }
    __syncthreads();
    floatx4 acc[RT][2];
    #pragma unroll
    for (int rt = 0; rt < RT; rt++)
      #pragma unroll
      for (int c = 0; c < 2; c++) acc[rt][c] = (floatx4){0.f, 0.f, 0.f, 0.f};
    {
      short8 bfr0 = *(const short8*)(eeW1 + (((size_t)(wave * 2 + 0)) * 64 + lane) * 8);
      short8 bfr1 = *(const short8*)(eeW1 + (((size_t)(wave * 2 + 1)) * 64 + lane) * 8);
      #pragma unroll
      for (int rt = 0; rt < RT; rt++) {
        short8 a = *(const short8*)(&Zt[(rt * 16 + colq) * SK + quad * 8]);
        acc[rt][0] = __builtin_amdgcn_mfma_f32_16x16x32_bf16(a, bfr0, acc[rt][0], 0, 0, 0);
        acc[rt][1] = __builtin_amdgcn_mfma_f32_16x16x32_bf16(a, bfr1, acc[rt][1], 0, 0, 0);
      }
    }
    __syncthreads();
    #pragma unroll
    for (int c = 0; c < 2; c++) {
      int col = wave * 32 + c * 16 + colq;
      float bv = b2f(eeB1[col]);
      #pragma unroll
      for (int rt = 0; rt < RT; rt++)
        #pragma unroll
        for (int r = 0; r < 4; r++)
          Zt[(rt * 16 + quad * 4 + r) * SK + col] =
              __float2bfloat16(fmaxf(acc[rt][c][r] + bv, 0.f));
    }
    __syncthreads();
    floatx4 acc2[RT][2];
    #pragma unroll
    for (int rt = 0; rt < RT; rt++)
      #pragma unroll
      for (int c = 0; c < 2; c++) acc2[rt][c] = (floatx4){0.f, 0.f, 0.f, 0.f};
    #pragma unroll
    for (int ks = 0; ks < 4; ks++) {
      short8 bfr0 = *(const short8*)(eeW2 + (((size_t)(wave * 2 + 0) * 4 + ks) * 64 + lane) * 8);
      short8 bfr1 = *(const short8*)(eeW2 + (((size_t)(wave * 2 + 1) * 4 + ks) * 64 + lane) * 8);
      #pragma unroll
      for (int rt = 0; rt < RT; rt++) {
        short8 a = *(const short8*)(&Zt[(rt * 16 + colq) * SK + ks * 32 + quad * 8]);
        acc2[rt][0] = __builtin_amdgcn_mfma_f32_16x16x32_bf16(a, bfr0, acc2[rt][0], 0, 0, 0);
        acc2[rt][1] = __builtin_amdgcn_mfma_f32_16x16x32_bf16(a, bfr1, acc2[rt][1], 0, 0, 0);
      }
    }
    #pragma unroll
    for (int c = 0; c < 2; c++) {
      int col = wave * 32 + c * 16 + colq;
      float bv = b2f(eeB2[col]);
      #pragma unroll
      for (int rt = 0; rt < RT; rt++)
        #pragma unroll
        for (int r = 0; r < 4; r++) {
          int grow = row0 + rt * 16 + quad * 4 + r;
          if (grow < E)
            h_edges[(size_t)grow * HDIM + col] = __float2bfloat16(acc2[rt][c][r] + bv);
        }
    }
    return;
  }

  // ---------------- encoder body: BM=64, K1=32 (14 used), type-sorted
  {
    constexpr int BM = 64, RT = 4, SK = 40, HS = 136;
    bf16* Zt = smem;
    bf16* Hid = smem + BM * SK;
    int idx = blockIdx.x - eeBlocks;
    int t = idx / ngrid64;
    int bx = idx - t * ngrid64;
    int rs = ts[t], re = ts[t + 1];
    int row0 = rs + bx * BM;
    if (row0 >= re) return;
    for (int i = tid; i < BM; i += 256) gIdx[i] = (row0 + i < re) ? perm[row0 + i] : -1;
    __syncthreads();
    for (int i = tid; i < BM * 32; i += 256) {
      int row = i >> 5, k = i & 31;
      int g = gIdx[row];
      bf16 v = __float2bfloat16(0.f);
      if (g >= 0 && k < 14) v = (k < 6) ? x[(size_t)g * 6 + k] : pe[(size_t)g * 8 + (k - 6)];
      Zt[row * SK + k] = v;
    }
    __syncthreads();
    const bf16* W1t = encW1 + (size_t)t * 4096;
    const bf16* W2t = encW2 + (size_t)t * 16384;
    floatx4 acc[RT][2];
    #pragma unroll
    for (int rt = 0; rt < RT; rt++)
      #pragma unroll
      for (int c = 0; c < 2; c++) acc[rt][c] = (floatx4){0.f, 0.f, 0.f, 0.f};
    {
      short8 bfr0 = *(const short8*)(W1t + (((size_t)(wave * 2 + 0)) * 64 + lane) * 8);
      short8 bfr1 = *(const short8*)(W1t + (((size_t)(wave * 2 + 1)) * 64 + lane) * 8);
      #pragma unroll
      for (int rt = 0; rt < RT; rt++) {
        short8 a = *(const short8*)(&Zt[(rt * 16 + colq) * SK + quad * 8]);
        acc[rt][0] = __builtin_amdgcn_mfma_f32_16x16x32_bf16(a, bfr0, acc[rt][0], 0, 0, 0);
        acc[rt][1] = __builtin_amdgcn_mfma_f32_16x16x32_bf16(a, bfr1, acc[rt][1], 0, 0, 0);
      }
    }
    #pragma unroll
    for (int c = 0; c < 2; c++) {
      int col = wave * 32 + c * 16 + colq;
      float bv = b2f(encB1[t * HDIM + col]);
      #pragma unroll
      for (int rt = 0; rt < RT; rt++)
        #pragma unroll
        for (int r = 0; r < 4; r++)
          Hid[(rt * 16 + quad * 4 + r) * HS + col] =
              __float2bfloat16(fmaxf(acc[rt][c][r] + bv, 0.f));
    }
    __syncthreads();
    floatx4 acc2[RT][2];
    #pragma unroll
    for (int rt = 0; rt < RT; rt++)
      #pragma unroll
      for (int c = 0; c < 2; c++) acc2[rt][c] = (floatx4){0.f, 0.f, 0.f, 0.f};
    #pragma unroll
    for (int ks = 0; ks < 4; ks++) {
      short8 bfr0 = *(const short8*)(W2t + (((size_t)(wave * 2 + 0) * 4 + ks) * 64 + lane) * 8);
      short8 bfr1 = *(const short8*)(W2t + (((size_t)(wave * 2 + 1) * 4 + ks) * 64 + lane) * 8);
      #pragma unroll
      for (int rt = 0; rt < RT; rt++) {
        short8 a = *(const short8*)(&Hid[(rt * 16 + colq) * HS + ks * 32 + quad * 8]);
        acc2[rt][0] = __builtin_amdgcn_mfma_f32_16x16x32_bf16(a, bfr0, acc2[rt][0], 0, 0, 0);
        acc2[rt][1] = __builtin_amdgcn_mfma_f32_16x16x32_bf16(a, bfr1, acc2[rt][1], 0, 0, 0);
      }
    }
    #pragma unroll
    for (int c = 0; c < 2; c++) {
      int col = wave * 32 + c * 16 + colq;
      float bv = b2f(encB2[t * HDIM + col]);
      #pragma unroll
      for (int rt = 0; rt < RT; rt++)
        #pragma unroll
        for (int r = 0; r < 4; r++) {
          int g = gIdx[rt * 16 + quad * 4 + r];
          if (g >= 0) h_nodes[(size_t)g * HDIM + col] = __float2bfloat16(acc2[rt][c][r] + bv);
        }
    }
  }
}

// -------------------------------------------------- typed decoder (type-sorted MFMA)
__global__ void __launch_bounds__(256) dec_kernel(
    const bf16* __restrict__ in0,
    const int* __restrict__ perm, const int* __restrict__ ts, const int* __restrict__ flagp,
    const bf16* __restrict__ W1p, const bf16* __restrict__ b1v,
    const bf16* __restrict__ W2p, const bf16* __restrict__ b2v,
    void* __restrict__ outp) {
  constexpr int BM = 64, RT = 4, SK = 136, HS = 136;
  int t = blockIdx.y;
  int rs = ts[t], re = ts[t + 1];
  int row0 = rs + blockIdx.x * BM;
  if (row0 >= re) return;
  __shared__ bf16 Zt[BM * SK];
  __shared__ bf16 Hid[BM * HS];
  __shared__ int gIdx[BM];
  const int tid = threadIdx.x;
  const int lane = tid & 63, wave = tid >> 6, colq = lane & 15, quad = lane >> 4;
  for (int i = tid; i < BM; i += 256) gIdx[i] = (row0 + i < re) ? perm[row0 + i] : -1;
  __syncthreads();
  {
    int row = tid >> 2, sub = tid & 3;
    int g = gIdx[row];
    #pragma unroll
    for (int j = 0; j < 4; j++) {
      int seg = j * 4 + sub;
      uint4 v = {0u, 0u, 0u, 0u};
      if (g >= 0) v = *(const uint4*)(in0 + (size_t)g * HDIM + seg * 8);
      *(uint4*)(&Zt[row * SK + seg * 8]) = v;
    }
  }
  __syncthreads();
  const bf16* W1t = W1p + (size_t)t * 16384;
  const bf16* W2t = W2p + (size_t)t * 16384;
  floatx4 acc[RT][2];
  #pragma unroll
  for (int rt = 0; rt < RT; rt++)
    #pragma unroll
    for (int c = 0; c < 2; c++) acc[rt][c] = (floatx4){0.f, 0.f, 0.f, 0.f};
  #pragma unroll
  for (int ks = 0; ks < 4; ks++) {
    short8 bfr0 = *(const short8*)(W1t + (((size_t)(wave * 2 + 0) * 4 + ks) * 64 + lane) * 8);
    short8 bfr1 = *(const short8*)(W1t + (((size_t)(wave * 2 + 1) * 4 + ks) * 64 + lane) * 8);
    #pragma unroll
    for (int rt = 0; rt < RT; rt++) {
      short8 a = *(const short8*)(&Zt[(rt * 16 + colq) * SK + ks * 32 + quad * 8]);
      acc[rt][0] = __builtin_amdgcn_mfma_f32_16x16x32_bf16(a, bfr0, acc[rt][0], 0, 0, 0);
      acc[rt][1] = __builtin_amdgcn_mfma_f32_16x16x32_bf16(a, bfr1, acc[rt][1], 0, 0, 0);
    }
  }
  #pragma unroll
  for (int c = 0; c < 2; c++) {
    int col = wave * 32 + c * 16 + colq;
    float bv = b2f(b1v[t * HDIM + col]);
    #pragma unroll
    for (int rt = 0; rt < RT; rt++)
      #pragma unroll
      for (int r = 0; r < 4; r++)
        Hid[(rt * 16 + quad * 4 + r) * HS + col] =
            __float2bfloat16(fmaxf(acc[rt][c][r] + bv, 0.f));
  }
  __syncthreads();
  floatx4 acc2[RT];
  #pragma unroll
  for (int rt = 0; rt < RT; rt++) acc2[rt] = (floatx4){0.f, 0.f, 0.f, 0.f};
  #pragma unroll
  for (int ks = 0; ks < 4; ks++) {
    short8 bfr0 = *(const short8*)(W2t + (((size_t)0 * 4 + ks) * 64 + lane) * 8);
    #pragma unroll
    for (int rt = 0; rt < RT; rt++) {
      short8 a = *(const short8*)(&Hid[(rt * 16 + colq) * HS + ks * 32 + quad * 8]);
      acc2[rt] = __builtin_amdgcn_mfma_f32_16x16x32_bf16(a, bfr0, acc2[rt], 0, 0, 0);
    }
  }
  if (wave == 0 && colq < 4) {
    int isBf = flagp[0];
    float bv = b2f(b2v[t * 4 + colq]);
    #pragma unroll
    for (int rt = 0; rt < RT; rt++)
      #pragma unroll
      for (int r = 0; r < 4; r++) {
        int g = gIdx[rt * 16 + quad * 4 + r];
        if (g >= 0) {
          float v = acc2[rt][r] + bv;
          if (isBf) ((bf16*)outp)[(size_t)g * 4 + colq] = __float2bfloat16(v);
          else      ((float*)outp)[(size_t)g * 4 + colq] = v;
        }
      }
  }
}

// ---------------------------------------------------------------- launcher
extern "C" void kernel_launch(void* const* d_in, const int* in_sizes, int n_in,
                              void* d_out, int out_size, void* d_ws, size_t ws_size,
                              hipStream_t stream) {
  const int* edge_index = (const int*)d_in[27];
  const int* node_types = (const int*)d_in[28];
  const int N = in_sizes[28];
  const int E = in_sizes[2] / 4;
  const int L = in_sizes[12] / HDIM;
  const int* srcI = edge_index;
  const int* dstI = edge_index + E;

  CanonDesc cd;
  int total = 0;
  for (int i = 0; i < NCANON; i++) { cd.src[i] = d_in[i]; cd.prefix[i] = total; total += in_sizes[i]; }
  cd.prefix[NCANON] = total;

  char* wsb = (char*)d_ws;
  size_t off = 0;
  auto alloc = [&](size_t bytes) -> void* {
    void* p = wsb + off;
    off += (bytes + 255) & ~(size_t)255;
    return p;
  };
  int*  flag      = (int*)alloc(256);
  bf16* arena     = (bf16*)alloc((size_t)total * 2);
  bf16* h_nodes   = (bf16*)alloc((size_t)N * HDIM * 2);
  bf16* h_edges   = (bf16*)alloc((size_t)E * HDIM * 2);
  float* m_node   = (float*)alloc((size_t)N * HDIM * 4);
  bf16* ysrcb     = (bf16*)alloc((size_t)N * HDIM * 2);
  bf16* ydstb     = (bf16*)alloc((size_t)N * HDIM * 2);
  bf16* eaS       = (bf16*)alloc((size_t)E * 4 * 2);
  int* counts     = (int*)alloc((size_t)N * 4);
  int* cursor     = (int*)alloc((size_t)N * 4);
  int* row_start  = (int*)alloc((size_t)(N + 1) * 4);
  int* bsum       = (int*)alloc(260 * 4);
  int* srcS       = (int*)alloc((size_t)E * 4);
  int* dstS       = (int*)alloc((size_t)E * 4);
  int* tsArr      = (int*)alloc(64);
  int* permT      = (int*)alloc((size_t)N * 4);
  bf16* eeW1p  = (bf16*)alloc(4096 * 2);
  bf16* eeW2p  = (bf16*)alloc(16384 * 2);
  bf16* encW1p = (bf16*)alloc(3 * 4096 * 2);
  bf16* encW2p = (bf16*)alloc(3 * 16384 * 2);
  bf16* decW1p = (bf16*)alloc(3 * 16384 * 2);
  bf16* decW2p = (bf16*)alloc(3 * 16384 * 2);
  bf16* euW1a  = (bf16*)alloc((size_t)L * 16384 * 2);
  bf16* euW1b  = (bf16*)alloc((size_t)L * 16384 * 2);
  bf16* euW1c  = (bf16*)alloc((size_t)L * 16384 * 2);
  bf16* euW2p  = (bf16*)alloc((size_t)L * 16384 * 2);
  bf16* nuW1p  = (bf16*)alloc((size_t)L * 32768 * 2);
  bf16* nuW2p  = (bf16*)alloc((size_t)L * 16384 * 2);
  bf16* fuW1p  = (bf16*)alloc((size_t)L * 16384 * 2);
  bf16* fuW2p  = (bf16*)alloc((size_t)L * 16384 * 2);

  const bf16* cX     = arena + cd.prefix[0];
  const bf16* cPE    = arena + cd.prefix[1];
  const bf16* cEA    = arena + cd.prefix[2];
  const bf16* cEncW1 = arena + cd.prefix[3];
  const bf16* cEncB1 = arena + cd.prefix[4];
  const bf16* cEncW2 = arena + cd.prefix[5];
  const bf16* cEncB2 = arena + cd.prefix[6];
  const bf16* cEeW1  = arena + cd.prefix[7];
  const bf16* cEeB1  = arena + cd.prefix[8];
  const bf16* cEeW2  = arena + cd.prefix[9];
  const bf16* cEeB2  = arena + cd.prefix[10];
  const bf16* cEuW1  = arena + cd.prefix[11];
  const bf16* cEuB1  = arena + cd.prefix[12];
  const bf16* cEuW2  = arena + cd.prefix[13];
  const bf16* cEuB2  = arena + cd.prefix[14];
  const bf16* cNuW1  = arena + cd.prefix[15];
  const bf16* cNuB1  = arena + cd.prefix[16];
  const bf16* cNuW2  = arena + cd.prefix[17];
  const bf16* cNuB2  = arena + cd.prefix[18];
  const bf16* cFuW1  = arena + cd.prefix[19];
  const bf16* cFuB1  = arena + cd.prefix[20];
  const bf16* cFuW2  = arena + cd.prefix[21];
  const bf16* cFuB2  = arena + cd.prefix[22];
  const bf16* cDecW1 = arena + cd.prefix[23];
  const bf16* cDecB1 = arena + cd.prefix[24];
  const bf16* cDecW2 = arena + cd.prefix[25];
  const bf16* cDecB2 = arena + cd.prefix[26];

  // canon (+ zero counts/cursor, contiguous 256-aligned region)
  int canonBlocks = (total + 255) / 256;
  size_t zbytes = (size_t)((char*)cursor - (char*)counts) + (size_t)N * 4;
  int zquads = (int)(zbytes / 16);
  int zBlocks = (zquads + 255) / 256;
  canon_kernel<<<canonBlocks + zBlocks, 256, 0, stream>>>(
      cd, (const unsigned short*)d_in[0], flag, arena, total, canonBlocks,
      (uint4*)counts, zquads);

  // hist + tsort (one dispatch, 1024 threads)
  int hb = (E + 1023) / 1024;
  hist_tsort_kernel<<<hb + 1, 1024, 0, stream>>>(dstI, counts, E, hb,
                                                 node_types, tsArr, permT, N);

  PackJobs PJ;
  int nj = 0;
  PJ.j[nj++] = {cEeW1, eeW1p, 4, 1, 128};
  PJ.j[nj++] = {cEeW2, eeW2p, 128, 4, 128};
  for (int l = 0; l < L; l++) {
    const bf16* w1 = cEuW1 + (size_t)l * 384 * HDIM;
    PJ.j[nj++] = {w1,                 euW1a + (size_t)l * 16384, 128, 4, 128};
    PJ.j[nj++] = {w1 + 128 * HDIM,    euW1b + (size_t)l * 16384, 128, 4, 128};
    PJ.j[nj++] = {w1 + 256 * HDIM,    euW1c + (size_t)l * 16384, 128, 4, 128};
    PJ.j[nj++] = {cEuW2 + (size_t)l * HDIM * HDIM, euW2p + (size_t)l * 16384, 128, 4, 128};
    PJ.j[nj++] = {cNuW1 + (size_t)l * 256 * HDIM,  nuW1p + (size_t)l * 32768, 256, 8, 128};
    PJ.j[nj++] = {cNuW2 + (size_t)l * HDIM * HDIM, nuW2p + (size_t)l * 16384, 128, 4, 128};
    PJ.j[nj++] = {cFuW1 + (size_t)l * HDIM * HDIM, fuW1p + (size_t)l * 16384, 128, 4, 128};
    PJ.j[nj++] = {cFuW2 + (size_t)l * HDIM * HDIM, fuW2p + (size_t)l * 16384, 128, 4, 128};
  }
  for (int t = 0; t < 3; t++) {
    PJ.j[nj++] = {cEncW1 + (size_t)t * 14 * HDIM,   encW1p + (size_t)t * 4096, 14, 1, 128};
    PJ.j[nj++] = {cEncW2 + (size_t)t * HDIM * HDIM, encW2p + (size_t)t * 16384, 128, 4, 128};
    PJ.j[nj++] = {cDecW1 + (size_t)t * HDIM * HDIM, decW1p + (size_t)t * 16384, 128, 4, 128};
    PJ.j[nj++] = {cDecW2 + (size_t)t * HDIM * 4,    decW2p + (size_t)t * 16384, 128, 4, 4};
  }
  pack_all_kernel<<<dim3(16, nj), 256, 0, stream>>>(PJ);

  int nb = (N + 255) / 256;
  scan1_kernel<<<nb, 256, 0, stream>>>(counts, bsum, N);
  scan2_kernel<<<1, 64, 0, stream>>>(bsum, nb);
  scan3_kernel<<<nb, 256, 0, stream>>>(counts, bsum, row_start, N, nb);
  scatter_kernel<<<(E + 255) / 256, 256, 0, stream>>>(srcI, dstI, row_start, cursor,
                                                      cEA, eaS, srcS, dstS, E);

  int ngrid64  = (N + 63) / 64;
  int egrid32  = (E + 31) / 32;
  int egrid128 = (E + 127) / 128;

  // fused encoder + edge-encoder
  encee_kernel<<<egrid128 + 3 * ngrid64, 256, 0, stream>>>(
      egrid128, ngrid64,
      eaS, eeW1p, cEeB1, eeW2p, cEeB2, h_edges, E,
      cX, cPE, permT, tsArr, encW1p, cEncB1, encW2p, cEncB2, h_nodes);

  for (int l = 0; l < L; l++) {
    if (l == 0) {
      ygemm_kernel<<<dim3(ngrid64, 2), 256, 0, stream>>>(
          h_nodes, euW1a, euW1b, ysrcb, ydstb, m_node, N);
    }
    if (l + 1 < L) {
      eu_kernel<32, true><<<egrid32, 256, 0, stream>>>(
          h_edges, ysrcb, ydstb, srcS, dstS,
          euW1c + (size_t)l * 16384, cEuB1 + l * HDIM,
          euW2p + (size_t)l * 16384, cEuB2 + l * HDIM, h_edges, m_node, E);
    } else {
      eu_kernel<32, false><<<egrid32, 256, 0, stream>>>(
          h_edges, ysrcb, ydstb, srcS, dstS,
          euW1c + (size_t)l * 16384, cEuB1 + l * HDIM,
          euW2p + (size_t)l * 16384, cEuB2 + l * HDIM, h_edges, m_node, E);
    }
    bool hasNext = (l + 1 < L);
    node_kernel<<<ngrid64, 256, 0, stream>>>(
        h_nodes, m_node,
        nuW1p + (size_t)l * 32768, cNuB1 + l * HDIM,
        nuW2p + (size_t)l * 16384, cNuB2 + l * HDIM,
        fuW1p + (size_t)l * 16384, cFuB1 + l * HDIM,
        fuW2p + (size_t)l * 16384, cFuB2 + l * HDIM,
        hasNext ? euW1a + (size_t)(l + 1) * 16384 : nullptr,
        hasNext ? euW1b + (size_t)(l + 1) * 16384 : nullptr,
        ysrcb, ydstb, h_nodes, N);
  }

  dec_kernel<<<dim3(ngrid64, 3), 256, 0, stream>>>(
      h_nodes, permT, tsArr, flag, decW1p, cDecB1, decW2p, cDecB2, d_out);
  (void)n_in; (void)ws_size;
}